// Round 5
// baseline (232.372 us; speedup 1.0000x reference)
//
#include <hip/hip_runtime.h>
#include <hip/hip_bf16.h>
#include <math.h>
#include <stdint.h>

#define BDIM 2
#define NDIM 512
#define HID 768
#define BIAF 256
#define CLS 14
#define DD 257   // BIAF+1
#define NPOS 30
#define SDIM 25
#define HSZ 539  // 2*257+25
#define PK 288   // padded contraction length (i and j), 9*32
#define ASTRIDE 296  // A-slab row stride (elems): 16B-slot stride 37 (odd) -> bank-spread

// Tiled operand layout: logical [R][C] bf16 matrices stored as contiguous
// 1KB tiles [R/16][C/32][16][32].  A wave's MFMA fragment read (lane ->
// l16*32 + quad*8) covers exactly one tile = 64 lanes x 16B CONTIGUOUS:
// perfectly coalesced, full L2-sector utilization, no LDS staging needed.
// h1/t1: [b][m>>4][f>>5][16][32] (32 m-tiles x 9 f-tiles per b)
// packW: [k][j>>4][i>>5][16][32] (18 j-tiles x 9 i-tiles per k)

typedef unsigned short ushort_t;
typedef __attribute__((ext_vector_type(8))) short short8;   // 8 bf16
typedef __attribute__((ext_vector_type(4))) float floatx4;  // 4 f32
typedef __attribute__((ext_vector_type(4))) unsigned short ushort4_t;

#define MFMA16(a, b, c) __builtin_amdgcn_mfma_f32_16x16x32_bf16((a), (b), (c), 0, 0, 0)

__device__ inline float bf2f(ushort_t u) {
    union { unsigned int i; float f; } c; c.i = ((unsigned)u) << 16; return c.f;
}
__device__ inline ushort_t f2bf(float f) {
    __hip_bfloat16 h = __float2bfloat16(f);
    return *(ushort_t*)&h;
}

// XCD-aware chunked swizzle (T1, bijective when nwg % 8 == 0).
__device__ inline int xcd_swz(int bid, int nwg) {
    int q = nwg >> 3;
    return (bid & 7) * q + (bid >> 3);
}

// ---------------------------------------------------------------------------
// prep_all: repack_t -> tiled packW (blocks 0..1133) + splits/pads (1134..3949)
// ---------------------------------------------------------------------------
__global__ __launch_bounds__(256) void prep_all(
    const float* __restrict__ biafW, ushort_t* __restrict__ packW,
    const float* __restrict__ x, const float* __restrict__ y,
    const float* __restrict__ m1w, const float* __restrict__ m2w,
    const float* __restrict__ hw,  const float* __restrict__ tw,
    ushort_t* __restrict__ xhi, ushort_t* __restrict__ xlo,
    ushort_t* __restrict__ yhi, ushort_t* __restrict__ ylo,
    ushort_t* __restrict__ whi, ushort_t* __restrict__ wlo,
    ushort_t* __restrict__ h1hi, ushort_t* __restrict__ h1lo,
    ushort_t* __restrict__ t1hi, ushort_t* __restrict__ t1lo)
{
    const int bid = blockIdx.x;
    if (bid < 1134) {
        // ---- repack biafW[k][i][j] -> tiled packW[k][j>>4][i>>5][16][32] ----
        __shared__ float tile[32][33];
        const int ix = bid % 9;            // i0/32
        const int jy = (bid / 9) % 9;      // j0/32
        const int k  = bid / 81;
        const int i0 = ix * 32, j0 = jy * 32;
        const int r8 = threadIdx.x >> 5;
        const int c  = threadIdx.x & 31;
        #pragma unroll
        for (int rr = 0; rr < 4; ++rr) {
            int r = rr * 8 + r8;
            int gi = i0 + r, gj = j0 + c;
            tile[r][c] = (gi < DD && gj < DD) ? biafW[((size_t)k * DD + gi) * DD + gj] : 0.f;
        }
        __syncthreads();
        #pragma unroll
        for (int rr = 0; rr < 4; ++rr) {
            int jr = rr * 8 + r8;
            int j = j0 + jr;
            size_t addr = ((size_t)(k * 18 + (j >> 4)) * 9 + ix) * 512 + (j & 15) * 32 + c;
            packW[addr] = f2bf(tile[c][jr]);
        }
        return;
    }
    int tg = (bid - 1134) * 256 + threadIdx.x;
    if (tg < 196608) {
        int mat = tg / 49152;
        int e0  = (tg % 49152) * 4;
        const float* src = (mat == 0) ? m1w : (mat == 1) ? m2w : (mat == 2) ? hw : tw;
        float4 v = *(const float4*)(src + e0);
        size_t o = (size_t)mat * 196608 + e0;
        ushort4_t h, lo;
        h[0] = f2bf(v.x); lo[0] = f2bf(v.x - bf2f(h[0]));
        h[1] = f2bf(v.y); lo[1] = f2bf(v.y - bf2f(h[1]));
        h[2] = f2bf(v.z); lo[2] = f2bf(v.z - bf2f(h[2]));
        h[3] = f2bf(v.w); lo[3] = f2bf(v.w - bf2f(h[3]));
        *(ushort4_t*)(whi + o) = h;
        *(ushort4_t*)(wlo + o) = lo;
    } else if (tg < 589824) {
        int t = tg - 196608;
        int which = t / 196608;
        int e0 = (t % 196608) * 4;
        const float* src = which ? y : x;
        float4 v = *(const float4*)(src + e0);
        ushort4_t h, lo;
        h[0] = f2bf(v.x); lo[0] = f2bf(v.x - bf2f(h[0]));
        h[1] = f2bf(v.y); lo[1] = f2bf(v.y - bf2f(h[1]));
        h[2] = f2bf(v.z); lo[2] = f2bf(v.z - bf2f(h[2]));
        h[3] = f2bf(v.w); lo[3] = f2bf(v.w - bf2f(h[3]));
        *(ushort4_t*)((which ? yhi : xhi) + e0) = h;
        *(ushort4_t*)((which ? ylo : xlo) + e0) = lo;
    } else {
        // pads in TILED h1/t1: f-tile 8 (cols 256..287); col 256 = 1.0 on hi
        int idx = tg - 589824;                 // 0..131071
        int plane = idx >> 15;
        int tok = (idx >> 5) & 1023;
        int c   = idx & 31;                    // feature 256 + c
        int bb = tok >> 9, m = tok & 511;
        ushort_t* dst = (plane == 0) ? h1hi : (plane == 1) ? h1lo : (plane == 2) ? t1hi : t1lo;
        ushort_t val = (c == 0 && (plane == 0 || plane == 2)) ? (ushort_t)0x3F80 : (ushort_t)0;
        dst[((size_t)(bb * 32 + (m >> 4)) * 9 + 8) * 512 + (m & 15) * 32 + c] = val;
    }
}

// ---------------------------------------------------------------------------
// proj_mfma: direct-load MFMA, pre-split operands, 3-term. 1D grid 512,
// XCD-swizzled. wave tile = 16 tokens x 32 features. h1/t1 written TILED.
// ---------------------------------------------------------------------------
__global__ __launch_bounds__(256) void proj_mfma(
    const ushort_t* __restrict__ xhi, const ushort_t* __restrict__ xlo,
    const ushort_t* __restrict__ yhi, const ushort_t* __restrict__ ylo,
    const ushort_t* __restrict__ whi, const ushort_t* __restrict__ wlo,
    const float* __restrict__ m1b, const float* __restrict__ m2b,
    const float* __restrict__ hb,  const float* __restrict__ tb,
    ushort_t* __restrict__ h1hi, ushort_t* __restrict__ h1lo,
    ushort_t* __restrict__ t1hi, ushort_t* __restrict__ t1lo,
    float* __restrict__ headf, float* __restrict__ tailf)
{
    const int flat = xcd_swz(blockIdx.x, 512);
    const int ft = flat & 7;
    const int mt = (flat >> 3) & 15;
    const int proj = flat >> 7;
    const int wave = threadIdx.x >> 6, L = threadIdx.x & 63;
    const int quad = L >> 4, l16 = L & 15;
    const int tok0 = mt * 64 + wave * 16;
    const int f0 = ft * 32;

    const ushort_t* ahi_p = (proj == 1) ? yhi : xhi;
    const ushort_t* alo_p = (proj == 1) ? ylo : xlo;
    const float* bias = (proj == 0) ? m1b : (proj == 1) ? m2b : (proj == 2) ? hb : tb;

    const size_t aoff = (size_t)(tok0 + l16) * HID + quad * 8;
    const size_t wbase = (size_t)proj * BIAF * HID;
    const size_t b0 = wbase + (size_t)(f0 + l16) * HID + quad * 8;
    const size_t b1 = wbase + (size_t)(f0 + 16 + l16) * HID + quad * 8;

    floatx4 acc0 = {0.f, 0.f, 0.f, 0.f}, acc1 = {0.f, 0.f, 0.f, 0.f};
    #pragma unroll 4
    for (int k0 = 0; k0 < HID; k0 += 32) {
        short8 ah  = *(const short8*)(ahi_p + aoff + k0);
        short8 al  = *(const short8*)(alo_p + aoff + k0);
        short8 bh0 = *(const short8*)(whi + b0 + k0);
        short8 bl0 = *(const short8*)(wlo + b0 + k0);
        short8 bh1 = *(const short8*)(whi + b1 + k0);
        short8 bl1 = *(const short8*)(wlo + b1 + k0);
        acc0 = MFMA16(ah, bh0, acc0);
        acc1 = MFMA16(ah, bh1, acc1);
        acc0 = MFMA16(al, bh0, acc0);
        acc1 = MFMA16(al, bh1, acc1);
        acc0 = MFMA16(ah, bl0, acc0);
        acc1 = MFMA16(ah, bl1, acc1);
    }

    #pragma unroll
    for (int nf = 0; nf < 2; ++nf) {
        floatx4 a = nf ? acc1 : acc0;
        int feat = f0 + nf * 16 + l16;
        float bv = bias[feat];
        #pragma unroll
        for (int r = 0; r < 4; ++r) {
            int tok = tok0 + quad * 4 + r;
            float v = a[r] + bv;
            if (proj <= 1) {
                float g = 0.5f * v * (1.0f + erff(v * 0.70710678118654752f));
                ushort_t h = f2bf(g);
                ushort_t lo = f2bf(g - bf2f(h));
                int bb = tok >> 9, m = tok & 511;
                size_t ad = ((size_t)(bb * 32 + (m >> 4)) * 9 + (feat >> 5)) * 512
                          + (m & 15) * 32 + (feat & 31);
                if (proj == 0) { h1hi[ad] = h; h1lo[ad] = lo; }
                else           { t1hi[ad] = h; t1lo[ad] = lo; }
            } else {
                float lv = (v >= 0.f) ? v : 0.01f * v;
                if (proj == 2) headf[(size_t)tok * 256 + feat] = lv;
                else           tailf[(size_t)tok * 256 + feat] = lv;
            }
        }
    }
}

// ---------------------------------------------------------------------------
// hk_tk_sk: blocks 0..127: hk/tk; 128..129: sk.
// ---------------------------------------------------------------------------
__global__ __launch_bounds__(256) void hk_tk_sk(
    const float* __restrict__ headf, const float* __restrict__ tailf,
    const float* __restrict__ W, const float* __restrict__ semb,
    float* __restrict__ hk, float* __restrict__ tk, float* __restrict__ skp)
{
    if (blockIdx.x >= 128) {
        int idx = (blockIdx.x - 128) * 256 + threadIdx.x;
        if (idx < CLS * NPOS) {
            int k = idx / NPOS, d = idx % NPOS;
            float acc = 0.f;
            for (int h = 0; h < SDIM; ++h)
                acc += semb[d*SDIM + h] * W[k*HSZ + 2*DD + h];
            skp[idx] = acc;
        }
        return;
    }
    int p = blockIdx.x * 256 + threadIdx.x;
    int which = p >> 14;
    int idx = p & 16383;
    int tok = idx >> 4;
    int k = idx & 15;
    if (k >= CLS) return;
    const float* row = (which ? tailf : headf) + (size_t)tok * 256;
    const float* wr = W + (size_t)k * HSZ + (which ? DD : 0);
    float acc = 0.f;
    for (int f4 = 0; f4 < 64; ++f4) {
        float4 rv = *(const float4*)(row + f4 * 4);
        acc += rv.x * wr[f4*4] + rv.y * wr[f4*4+1] + rv.z * wr[f4*4+2] + rv.w * wr[f4*4+3];
    }
    acc += wr[256];
    float* dst = which ? tk : hk;
    dst[(size_t)(tok >> 9) * CLS * NDIM + (size_t)k * NDIM + (tok & 511)] = acc;
}

// ---------------------------------------------------------------------------
// biaf_fused v2: tiled-direct-load, barrier-free phases.
// grid = 28 bk x 16 mt x 2 ns = 896 blocks (bk-major, XCD-swizzled), 256 thr.
// Phase A (redundant across ns): accA = h1[m-slab] . packW[k]^T in registers,
//   direct 1KB-tile loads (coalesced), no LDS, no barriers.
//   wave (mi=w>>1, jh=w&1): 16 m-rows x 9 j-tiles.  MFMA order == R4.
// A-slab -> LDS (bf16, same rounding), ONE barrier.
// Phase B: out cols [ns*256, +256): direct t1 tile loads, no barriers.
//   wave (mi2=w>>1, nh=w&1); per nt: js 0..8 x nf 0..3 {hi,lo}. order == R4.
// LDS 18.7KB, __launch_bounds__(256,4) -> 4 blocks/CU.
// ---------------------------------------------------------------------------
__global__ __launch_bounds__(256, 4) void biaf_fused(
    const ushort_t* __restrict__ h1hi, const ushort_t* __restrict__ h1lo,
    const ushort_t* __restrict__ packW,
    const ushort_t* __restrict__ t1hi, const ushort_t* __restrict__ t1lo,
    const float* __restrict__ hk, const float* __restrict__ tk,
    const float* __restrict__ sk,
    float* __restrict__ out)
{
    __shared__ __align__(16) ushort_t Aslab[32 * ASTRIDE];   // 18.5 KB
    __shared__ float skr[NPOS];

    const int flat = xcd_swz(blockIdx.x, 896);
    const int ns = flat & 1, mt = (flat >> 1) & 15, bk = flat >> 5;  // bk-major
    const int b = bk / CLS, k = bk % CLS;
    const int tid = threadIdx.x;
    if (tid < NPOS) skr[tid] = sk[k * NPOS + tid];
    const int wave = tid >> 6, L = tid & 63;
    const int quad = L >> 4, l16 = L & 15;
    const int frag = l16 * 32 + quad * 8;      // fragment offset in a 1KB tile
    const int m0 = mt * 32;

    // ---------------- phase A (direct tile loads, no barriers) ----------------
    const int mi = wave >> 1, jh = wave & 1;
    const ushort_t* Ah_t = h1hi + (size_t)((b * 32 + mt * 2 + mi) * 9) * 512;
    const ushort_t* Al_t = h1lo + (size_t)((b * 32 + mt * 2 + mi) * 9) * 512;
    const ushort_t* Wp   = packW + (size_t)k * 18 * 9 * 512;

    floatx4 accA[9];
    #pragma unroll
    for (int t = 0; t < 9; ++t)
        #pragma unroll
        for (int r = 0; r < 4; ++r) accA[t][r] = 0.f;

    #pragma unroll 3
    for (int it = 0; it < 9; ++it) {
        short8 ah = *(const short8*)(Ah_t + it * 512 + frag);
        short8 al = *(const short8*)(Al_t + it * 512 + frag);
        #pragma unroll
        for (int t = 0; t < 9; ++t) {
            short8 bt = *(const short8*)(Wp + (size_t)((jh * 9 + t) * 9 + it) * 512 + frag);
            accA[t] = MFMA16(ah, bt, accA[t]);
            accA[t] = MFMA16(al, bt, accA[t]);
        }
    }

    // write A-slab (bf16, same rounding as before)
    #pragma unroll
    for (int t = 0; t < 9; ++t) {
        int jb = (jh * 9 + t) * 16 + l16;
        #pragma unroll
        for (int r = 0; r < 4; ++r) {
            int row = mi * 16 + quad * 4 + r;
            Aslab[row * ASTRIDE + jb] = f2bf(accA[t][r]);
        }
    }
    __syncthreads();

    // ---------------- phase B (direct tile loads, no barriers) ----------------
    const int mi2 = wave >> 1, nh = wave & 1;
    const size_t tb0 = (size_t)(b * 32) * 9 * 512;
    const size_t obase = (size_t)bk * NDIM;

    for (int ntl = 0; ntl < 2; ++ntl) {
        const int nt = ns * 2 + ntl;
        floatx4 accB[4];
        #pragma unroll
        for (int nf = 0; nf < 4; ++nf)
            #pragma unroll
            for (int r = 0; r < 4; ++r) accB[nf][r] = 0.f;

        #pragma unroll 3
        for (int js = 0; js < 9; ++js) {
            short8 a = *(const short8*)(Aslab + (mi2 * 16 + l16) * ASTRIDE + js * 32 + quad * 8);
            #pragma unroll
            for (int nf = 0; nf < 4; ++nf) {
                const size_t toff = tb0 + (size_t)((nt * 8 + nh * 4 + nf) * 9 + js) * 512 + frag;
                short8 bh = *(const short8*)(t1hi + toff);
                short8 bl = *(const short8*)(t1lo + toff);
                accB[nf] = MFMA16(a, bh, accB[nf]);
                accB[nf] = MFMA16(a, bl, accB[nf]);
            }
        }

        // epilogue for this n-tile (identical math/order to R4)
        int n0 = nt * 128;
        #pragma unroll
        for (int r = 0; r < 4; ++r) {
            int row = m0 + mi2 * 16 + quad * 4 + r;
            float hv = hk[obase + row];
            #pragma unroll
            for (int nf = 0; nf < 4; ++nf) {
                int col = n0 + nh * 64 + nf * 16 + l16;
                int d = col - row; d = d < -15 ? -15 : (d > 14 ? 14 : d); d += 15;
                out[(obase + row) * NDIM + col] = accB[nf][r] + hv + tk[obase + col] + skr[d];
            }
        }
    }
}

// ---------------------------------------------------------------------------
extern "C" void kernel_launch(void* const* d_in, const int* in_sizes, int n_in,
                              void* d_out, int out_size, void* d_ws, size_t ws_size,
                              hipStream_t stream) {
    const float* x    = (const float*)d_in[0];
    const float* y    = (const float*)d_in[1];
    // d_in[2] = z : unused
    const float* m1w  = (const float*)d_in[3];
    const float* m1b  = (const float*)d_in[4];
    const float* m2w  = (const float*)d_in[5];
    const float* m2b  = (const float*)d_in[6];
    const float* hw   = (const float*)d_in[7];
    const float* hb   = (const float*)d_in[8];
    const float* tw   = (const float*)d_in[9];
    const float* tb   = (const float*)d_in[10];
    const float* biafW= (const float*)d_in[11];
    const float* W    = (const float*)d_in[12];
    const float* semb = (const float*)d_in[13];

    char* p = (char*)d_ws;
    float* hk   = (float*)p;                    p += 57344;
    float* tk   = (float*)p;                    p += 57344;
    float* skp  = (float*)p;                    p += 2048;
    float* headf= (float*)p;                    p += 1048576;
    float* tailf= (float*)p;                    p += 1048576;
    ushort_t* h1hi = (ushort_t*)p;              p += 589824;   // tiled [2][32][9][16][32]
    ushort_t* h1lo = (ushort_t*)p;              p += 589824;
    ushort_t* t1hi = (ushort_t*)p;              p += 589824;
    ushort_t* t1lo = (ushort_t*)p;              p += 589824;
    ushort_t* packW= (ushort_t*)p;              p += 2322432;  // tiled 14*18*9*512*2
    ushort_t* whi  = (ushort_t*)p;              p += 1572864;  // 4*256*768*2
    ushort_t* wlo  = (ushort_t*)p;              p += 1572864;
    ushort_t* xhi  = (ushort_t*)p;              p += 1572864;  // 1024*768*2
    ushort_t* xlo  = (ushort_t*)p;              p += 1572864;
    ushort_t* yhi  = (ushort_t*)p;              p += 1572864;
    ushort_t* ylo  = (ushort_t*)p;              p += 1572864;

    prep_all<<<3950, 256, 0, stream>>>(biafW, packW, x, y, m1w, m2w, hw, tw,
                                       xhi, xlo, yhi, ylo, whi, wlo,
                                       h1hi, h1lo, t1hi, t1lo);
    proj_mfma<<<512, 256, 0, stream>>>(xhi, xlo, yhi, ylo, whi, wlo,
                                       m1b, m2b, hb, tb,
                                       h1hi, h1lo, t1hi, t1lo, headf, tailf);
    hk_tk_sk<<<130, 256, 0, stream>>>(headf, tailf, W, semb, hk, tk, skp);
    biaf_fused<<<896, 256, 0, stream>>>(h1hi, h1lo, packW, t1hi, t1lo,
                                        hk, tk, skp, (float*)d_out);
}

// Round 6
// 180.073 us; speedup vs baseline: 1.2904x; 1.2904x over previous
//
#include <hip/hip_runtime.h>
#include <hip/hip_bf16.h>
#include <math.h>
#include <stdint.h>

#define BDIM 2
#define NDIM 512
#define HID 768
#define BIAF 256
#define CLS 14
#define DD 257   // BIAF+1
#define NPOS 30
#define SDIM 25
#define HSZ 539  // 2*257+25
#define PK 288   // padded contraction length (i and j), 9*32
#define PJ 384   // packW j-rows padding

typedef unsigned short ushort_t;
typedef __attribute__((ext_vector_type(8))) short short8;   // 8 bf16
typedef __attribute__((ext_vector_type(4))) float floatx4;  // 4 f32
typedef __attribute__((ext_vector_type(4))) unsigned short ushort4_t;

#define MFMA16(a, b, c) __builtin_amdgcn_mfma_f32_16x16x32_bf16((a), (b), (c), 0, 0, 0)

__device__ inline float bf2f(ushort_t u) {
    union { unsigned int i; float f; } c; c.i = ((unsigned)u) << 16; return c.f;
}
__device__ inline ushort_t f2bf(float f) {
    __hip_bfloat16 h = __float2bfloat16(f);
    return *(ushort_t*)&h;
}

// XCD-aware chunked swizzle (T1, bijective when nwg % 8 == 0).
__device__ inline int xcd_swz(int bid, int nwg) {
    int q = nwg >> 3;
    return (bid & 7) * q + (bid >> 3);
}

// async global->LDS, 16B per lane. LDS dest = wave-uniform base + lane*16.
__device__ inline void glds16(const ushort_t* g, const ushort_t* l) {
    __builtin_amdgcn_global_load_lds(
        (const __attribute__((address_space(1))) unsigned int*)(unsigned long long)(uintptr_t)g,
        (__attribute__((address_space(3))) unsigned int*)(unsigned int)(uintptr_t)l,
        16, 0, 0);
}

// ---------------------------------------------------------------------------
// Staged-tile LDS swizzle (rule #21: linear LDS dest via glds, pre-swizzled
// global source, swizzled read).  Seg = [16 rows][32 cols] bf16 (1KB);
// row-pairs form 128B super-rows of eight 16B slots; slot' = slot ^ (srow&7).
// srow/scol: which global (row, col-quad) lane L fetches; rbase: element
// offset of fragment (l16,quad) inside a seg.  Verified R1-R3.
// ---------------------------------------------------------------------------

// ---------------------------------------------------------------------------
// prep_all: fused repack_t (blocks 0..1511) + splits/pads (1512..4327).
// ---------------------------------------------------------------------------
__global__ __launch_bounds__(256) void prep_all(
    const float* __restrict__ biafW, ushort_t* __restrict__ packW,
    const float* __restrict__ x, const float* __restrict__ y,
    const float* __restrict__ m1w, const float* __restrict__ m2w,
    const float* __restrict__ hw,  const float* __restrict__ tw,
    ushort_t* __restrict__ xhi, ushort_t* __restrict__ xlo,
    ushort_t* __restrict__ yhi, ushort_t* __restrict__ ylo,
    ushort_t* __restrict__ whi, ushort_t* __restrict__ wlo,
    ushort_t* __restrict__ h1hi, ushort_t* __restrict__ h1lo,
    ushort_t* __restrict__ t1hi, ushort_t* __restrict__ t1lo)
{
    const int bid = blockIdx.x;
    if (bid < 1512) {
        __shared__ float tile[32][33];
        const int ix = bid % 9;
        const int jy = (bid / 9) % 12;
        const int k  = bid / 108;
        const int i0 = ix * 32, j0 = jy * 32;
        const int r8 = threadIdx.x >> 5;
        const int c  = threadIdx.x & 31;
        #pragma unroll
        for (int rr = 0; rr < 4; ++rr) {
            int r = rr * 8 + r8;
            int gi = i0 + r, gj = j0 + c;
            tile[r][c] = (gi < DD && gj < DD) ? biafW[((size_t)k * DD + gi) * DD + gj] : 0.f;
        }
        __syncthreads();
        #pragma unroll
        for (int rr = 0; rr < 4; ++rr) {
            int jr = rr * 8 + r8;
            packW[((size_t)k * PJ + (j0 + jr)) * PK + i0 + c] = f2bf(tile[c][jr]);
        }
        return;
    }
    int tg = (bid - 1512) * 256 + threadIdx.x;
    if (tg < 196608) {
        int mat = tg / 49152;
        int e0  = (tg % 49152) * 4;
        const float* src = (mat == 0) ? m1w : (mat == 1) ? m2w : (mat == 2) ? hw : tw;
        float4 v = *(const float4*)(src + e0);
        size_t o = (size_t)mat * 196608 + e0;
        ushort4_t h, lo;
        h[0] = f2bf(v.x); lo[0] = f2bf(v.x - bf2f(h[0]));
        h[1] = f2bf(v.y); lo[1] = f2bf(v.y - bf2f(h[1]));
        h[2] = f2bf(v.z); lo[2] = f2bf(v.z - bf2f(h[2]));
        h[3] = f2bf(v.w); lo[3] = f2bf(v.w - bf2f(h[3]));
        *(ushort4_t*)(whi + o) = h;
        *(ushort4_t*)(wlo + o) = lo;
    } else if (tg < 589824) {
        int t = tg - 196608;
        int which = t / 196608;
        int e0 = (t % 196608) * 4;
        const float* src = which ? y : x;
        float4 v = *(const float4*)(src + e0);
        ushort4_t h, lo;
        h[0] = f2bf(v.x); lo[0] = f2bf(v.x - bf2f(h[0]));
        h[1] = f2bf(v.y); lo[1] = f2bf(v.y - bf2f(h[1]));
        h[2] = f2bf(v.z); lo[2] = f2bf(v.z - bf2f(h[2]));
        h[3] = f2bf(v.w); lo[3] = f2bf(v.w - bf2f(h[3]));
        *(ushort4_t*)((which ? yhi : xhi) + e0) = h;
        *(ushort4_t*)((which ? ylo : xlo) + e0) = lo;
    } else {
        int idx = tg - 589824;                 // 0..131071
        int plane = idx >> 15;
        int tok = (idx >> 5) & 1023;
        int c   = 256 + (idx & 31);
        ushort_t* dst = (plane == 0) ? h1hi : (plane == 1) ? h1lo : (plane == 2) ? t1hi : t1lo;
        ushort_t val = (c == 256 && (plane == 0 || plane == 2)) ? (ushort_t)0x3F80 : (ushort_t)0;
        dst[(size_t)tok * PK + c] = val;
    }
}

// ---------------------------------------------------------------------------
// proj_mfma v5: glds-dbuf staged (R5 proved direct-L2 loads latency-bound:
// 66us @ 10% MfmaUtil / 7% HBM; glds async queue is the latency hider).
// 1D grid 512, XCD-swizzled. block = 64 tok x 32 feat; wave = 16 tok.
// Per k-step: 12 x 1KB segs (Ah4, Al4, Wh2, Wl2), dbuf 24KB, swizzled reads.
// MFMA accumulate order identical to R0-R3 -> bit-identical output.
// ---------------------------------------------------------------------------
__global__ __launch_bounds__(256) void proj_mfma(
    const ushort_t* __restrict__ xhi, const ushort_t* __restrict__ xlo,
    const ushort_t* __restrict__ yhi, const ushort_t* __restrict__ ylo,
    const ushort_t* __restrict__ whi, const ushort_t* __restrict__ wlo,
    const float* __restrict__ m1b, const float* __restrict__ m2b,
    const float* __restrict__ hb,  const float* __restrict__ tb,
    ushort_t* __restrict__ h1hi, ushort_t* __restrict__ h1lo,
    ushort_t* __restrict__ t1hi, ushort_t* __restrict__ t1lo,
    float* __restrict__ headf, float* __restrict__ tailf)
{
    __shared__ __align__(16) ushort_t Sh[2 * 6144];   // 2 x 12KB
    const int flat = xcd_swz(blockIdx.x, 512);
    const int ft = flat & 7;
    const int mt = (flat >> 3) & 15;
    const int proj = flat >> 7;
    const int wave = threadIdx.x >> 6, L = threadIdx.x & 63;
    const int quad = L >> 4, l16 = L & 15;
    const int sr = L >> 3, u = (L & 7) ^ sr;
    const int srow = 2 * sr + (u >> 2);
    const int scol = (u & 3) * 8;
    const int rbase = (l16 >> 1) * 64 + (((((l16 & 1) << 2) | quad) ^ (l16 >> 1)) * 8);
    const int tok0 = mt * 64 + wave * 16;
    const int f0 = ft * 32;

    const ushort_t* ahi_p = (proj == 1) ? yhi : xhi;
    const ushort_t* alo_p = (proj == 1) ? ylo : xlo;
    const float* bias = (proj == 0) ? m1b : (proj == 1) ? m2b : (proj == 2) ? hb : tb;

    const ushort_t* gAh = ahi_p + (size_t)(mt * 64) * HID;
    const ushort_t* gAl = alo_p + (size_t)(mt * 64) * HID;
    const size_t wbase = (size_t)proj * BIAF * HID;
    const ushort_t* gWh = whi + wbase + (size_t)f0 * HID;
    const ushort_t* gWl = wlo + wbase + (size_t)f0 * HID;

    auto stage = [&](int bo, int k0) {
        for (int s = wave; s < 12; s += 4) {
            const ushort_t* g;
            if (s < 4)       g = gAh + (size_t)(s * 16 + srow) * HID + k0 + scol;
            else if (s < 8)  g = gAl + (size_t)((s - 4) * 16 + srow) * HID + k0 + scol;
            else if (s < 10) g = gWh + (size_t)((s - 8) * 16 + srow) * HID + k0 + scol;
            else             g = gWl + (size_t)((s - 10) * 16 + srow) * HID + k0 + scol;
            glds16(g, Sh + bo * 6144 + s * 512);
        }
    };

    floatx4 acc0 = {0.f, 0.f, 0.f, 0.f}, acc1 = {0.f, 0.f, 0.f, 0.f};
    stage(0, 0);
    __syncthreads();
    int cur = 0;
    for (int t = 0; t < 24; ++t) {
        if (t < 23) stage(cur ^ 1, (t + 1) * 32);   // prefetch next k-step
        const ushort_t* B = Sh + cur * 6144;
        short8 ah  = *(const short8*)(B + wave * 512 + rbase);
        short8 al  = *(const short8*)(B + 2048 + wave * 512 + rbase);
        short8 bh0 = *(const short8*)(B + 4096 + rbase);
        short8 bh1 = *(const short8*)(B + 4608 + rbase);
        short8 bl0 = *(const short8*)(B + 5120 + rbase);
        short8 bl1 = *(const short8*)(B + 5632 + rbase);
        acc0 = MFMA16(ah, bh0, acc0);
        acc1 = MFMA16(ah, bh1, acc1);
        acc0 = MFMA16(al, bh0, acc0);
        acc1 = MFMA16(al, bh1, acc1);
        acc0 = MFMA16(ah, bl0, acc0);
        acc1 = MFMA16(ah, bl1, acc1);
        __syncthreads();
        cur ^= 1;
    }

    #pragma unroll
    for (int nf = 0; nf < 2; ++nf) {
        floatx4 a = nf ? acc1 : acc0;
        int feat = f0 + nf * 16 + l16;
        float bv = bias[feat];
        #pragma unroll
        for (int r = 0; r < 4; ++r) {
            int tok = tok0 + quad * 4 + r;
            float v = a[r] + bv;
            if (proj <= 1) {
                float g = 0.5f * v * (1.0f + erff(v * 0.70710678118654752f));
                ushort_t h = f2bf(g);
                ushort_t lo = f2bf(g - bf2f(h));
                if (proj == 0) { h1hi[(size_t)tok * PK + feat] = h; h1lo[(size_t)tok * PK + feat] = lo; }
                else           { t1hi[(size_t)tok * PK + feat] = h; t1lo[(size_t)tok * PK + feat] = lo; }
            } else {
                float lv = (v >= 0.f) ? v : 0.01f * v;
                if (proj == 2) headf[(size_t)tok * 256 + feat] = lv;
                else           tailf[(size_t)tok * 256 + feat] = lv;
            }
        }
    }
}

// ---------------------------------------------------------------------------
// mb_hk: fused mb_tile (blocks 0..671, XCD-swizzled) + hk_tk_sk (672..801).
// ---------------------------------------------------------------------------
__global__ __launch_bounds__(256) void mb_hk(
    const ushort_t* __restrict__ h1hi, const ushort_t* __restrict__ h1lo,
    const ushort_t* __restrict__ packW,
    ushort_t* __restrict__ Ab,
    const float* __restrict__ headf, const float* __restrict__ tailf,
    const float* __restrict__ W, const float* __restrict__ semb,
    float* __restrict__ hk, float* __restrict__ tk, float* __restrict__ skp)
{
    const int bid = blockIdx.x;
    if (bid >= 672) {
        const int hb = bid - 672;           // 0..129
        if (hb >= 128) {
            int idx = (hb - 128) * 256 + threadIdx.x;
            if (idx < CLS * NPOS) {
                int k = idx / NPOS, d = idx % NPOS;
                float acc = 0.f;
                for (int h = 0; h < SDIM; ++h)
                    acc += semb[d*SDIM + h] * W[k*HSZ + 2*DD + h];
                skp[idx] = acc;
            }
            return;
        }
        int p = hb * 256 + threadIdx.x;      // 32768 items
        int which = p >> 14;                 // 0=hk, 1=tk
        int idx = p & 16383;
        int tok = idx >> 4;
        int k = idx & 15;
        if (k >= CLS) return;
        const float* row = (which ? tailf : headf) + (size_t)tok * 256;
        const float* wr = W + (size_t)k * HSZ + (which ? DD : 0);
        float acc = 0.f;
        for (int f4 = 0; f4 < 64; ++f4) {
            float4 rv = *(const float4*)(row + f4 * 4);
            acc += rv.x * wr[f4*4] + rv.y * wr[f4*4+1] + rv.z * wr[f4*4+2] + rv.w * wr[f4*4+3];
        }
        acc += wr[256];
        float* dst = which ? tk : hk;
        dst[(size_t)(tok >> 9) * CLS * NDIM + (size_t)k * NDIM + (tok & 511)] = acc;
        return;
    }

    // ---- mb_tile, double-buffered, XCD-swizzled ----
    __shared__ ushort_t Ah[2 * 2048];   // 2 x 4KB
    __shared__ ushort_t Al[2 * 2048];   // 2 x 4KB
    __shared__ ushort_t Bt[2 * 3072];   // 2 x 6KB
    const int flat = xcd_swz(bid, 672);
    const int jt = flat % 3, mt = (flat / 3) % 8, bk = flat / 24;
    const int b = bk / CLS, k = bk % CLS;
    const int tid = threadIdx.x;
    const int wave = tid >> 6, L = tid & 63;
    const int quad = L >> 4, l16 = L & 15;
    const int sr = L >> 3, u = (L & 7) ^ sr;
    const int srow = 2 * sr + (u >> 2);        // row within 16-row segment
    const int scol = (u & 3) * 8;              // element col within 32
    const int rbase = (l16 >> 1) * 64 + ((((((l16 & 1) << 2) | quad)) ^ (l16 >> 1)) * 8);
    const int m0 = mt * 64, j0 = jt * 96;
    const int wm = (wave >> 1) * 32, wj = (wave & 1) * 48;

    const ushort_t* gAh = h1hi + (size_t)(b * NDIM + m0) * PK;
    const ushort_t* gAl = h1lo + (size_t)(b * NDIM + m0) * PK;
    const ushort_t* gB  = packW + ((size_t)k * PJ + j0) * PK;

    auto stage = [&](int bo, int k0) {
        for (int s = wave; s < 14; s += 4) {
            const ushort_t* g; const ushort_t* l;
            if (s < 4)      { l = Ah + bo * 2048 + s * 512;       g = gAh + (size_t)(s * 16 + srow) * PK + k0 + scol; }
            else if (s < 8) { l = Al + bo * 2048 + (s - 4) * 512; g = gAl + (size_t)((s - 4) * 16 + srow) * PK + k0 + scol; }
            else            { l = Bt + bo * 3072 + (s - 8) * 512; g = gB  + (size_t)((s - 8) * 16 + srow) * PK + k0 + scol; }
            glds16(g, l);
        }
    };

    floatx4 acc[2][3];
    #pragma unroll
    for (int mi = 0; mi < 2; ++mi)
        #pragma unroll
        for (int ni = 0; ni < 3; ++ni)
            #pragma unroll
            for (int r = 0; r < 4; ++r) acc[mi][ni][r] = 0.f;

    stage(0, 0);
    __syncthreads();
    int cur = 0;
    for (int t = 0; t < 9; ++t) {
        if (t < 8) stage(cur ^ 1, (t + 1) * 32);   // prefetch next tile
        short8 ah[2], al[2], bb[3];
        #pragma unroll
        for (int mi = 0; mi < 2; ++mi) {
            ah[mi] = *(const short8*)(Ah + cur * 2048 + (wm + mi * 16) * 32 + rbase);
            al[mi] = *(const short8*)(Al + cur * 2048 + (wm + mi * 16) * 32 + rbase);
        }
        #pragma unroll
        for (int ni = 0; ni < 3; ++ni)
            bb[ni] = *(const short8*)(Bt + cur * 3072 + (wj + ni * 16) * 32 + rbase);
        #pragma unroll
        for (int mi = 0; mi < 2; ++mi)
            #pragma unroll
            for (int ni = 0; ni < 3; ++ni) {
                acc[mi][ni] = MFMA16(ah[mi], bb[ni], acc[mi][ni]);
                acc[mi][ni] = MFMA16(al[mi], bb[ni], acc[mi][ni]);
            }
        __syncthreads();
        cur ^= 1;
    }

    ushort_t* Aout = Ab + (size_t)bk * NDIM * PK;
    #pragma unroll
    for (int mi = 0; mi < 2; ++mi) {
        #pragma unroll
        for (int r = 0; r < 4; ++r) {
            int row = m0 + wm + mi * 16 + quad * 4 + r;
            #pragma unroll
            for (int ni = 0; ni < 3; ++ni) {
                int col = j0 + wj + ni * 16 + l16;
                Aout[(size_t)row * PK + col] = f2bf(acc[mi][ni][r]);
            }
        }
    }
}

// ---------------------------------------------------------------------------
// mo_tile: out[bk][m][n] = sum_j A[bk][m][j]*t1[b][n][j] + hk + tk + sk
// tile 64x128, double-buffered glds staging, XOR-swizzled LDS.
// 1D grid 896, XCD-swizzled.
// ---------------------------------------------------------------------------
__global__ __launch_bounds__(256) void mo_tile(
    const ushort_t* __restrict__ Ab,
    const ushort_t* __restrict__ t1hi, const ushort_t* __restrict__ t1lo,
    const float* __restrict__ hk, const float* __restrict__ tk,
    const float* __restrict__ sk,
    float* __restrict__ out)
{
    __shared__ ushort_t At[2 * 2048];    // 2 x 4KB
    __shared__ ushort_t Bh[2 * 4096];    // 2 x 8KB
    __shared__ ushort_t Bl[2 * 4096];    // 2 x 8KB
    __shared__ float skr[NPOS];
    const int flat = xcd_swz(blockIdx.x, 896);
    const int nt = flat & 3, mt = (flat >> 2) & 7, bk = flat >> 5;
    const int b = bk / CLS, k = bk % CLS;
    const int tid = threadIdx.x;
    if (tid < NPOS) skr[tid] = sk[k * NPOS + tid];
    const int wave = tid >> 6, L = tid & 63;
    const int quad = L >> 4, l16 = L & 15;
    const int sr = L >> 3, u = (L & 7) ^ sr;
    const int srow = 2 * sr + (u >> 2);
    const int scol = (u & 3) * 8;
    const int rbase = (l16 >> 1) * 64 + ((((((l16 & 1) << 2) | quad)) ^ (l16 >> 1)) * 8);
    const int m0 = mt * 64, n0 = nt * 128;
    const int wm = (wave >> 1) * 32, wn = (wave & 1) * 64;

    const ushort_t* gA  = Ab + ((size_t)bk * NDIM + m0) * PK;
    const ushort_t* gBh = t1hi + (size_t)(b * NDIM + n0) * PK;
    const ushort_t* gBl = t1lo + (size_t)(b * NDIM + n0) * PK;

    auto stage = [&](int bo, int k0) {
        for (int s = wave; s < 20; s += 4) {
            const ushort_t* g; const ushort_t* l;
            if (s < 4)       { l = At + bo * 2048 + s * 512;         g = gA  + (size_t)(s * 16 + srow) * PK + k0 + scol; }
            else if (s < 12) { l = Bh + bo * 4096 + (s - 4) * 512;   g = gBh + (size_t)((s - 4) * 16 + srow) * PK + k0 + scol; }
            else             { l = Bl + bo * 4096 + (s - 12) * 512;  g = gBl + (size_t)((s - 12) * 16 + srow) * PK + k0 + scol; }
            glds16(g, l);
        }
    };

    floatx4 acc[2][4];
    #pragma unroll
    for (int mi = 0; mi < 2; ++mi)
        #pragma unroll
        for (int ni = 0; ni < 4; ++ni)
            #pragma unroll
            for (int r = 0; r < 4; ++r) acc[mi][ni][r] = 0.f;

    stage(0, 0);
    __syncthreads();
    int cur = 0;
    for (int t = 0; t < 9; ++t) {
        if (t < 8) stage(cur ^ 1, (t + 1) * 32);   // prefetch next tile
        short8 a[2], bh[4], bl[4];
        #pragma unroll
        for (int mi = 0; mi < 2; ++mi)
            a[mi] = *(const short8*)(At + cur * 2048 + (wm + mi * 16) * 32 + rbase);
        #pragma unroll
        for (int ni = 0; ni < 4; ++ni) {
            bh[ni] = *(const short8*)(Bh + cur * 4096 + (wn + ni * 16) * 32 + rbase);
            bl[ni] = *(const short8*)(Bl + cur * 4096 + (wn + ni * 16) * 32 + rbase);
        }
        #pragma unroll
        for (int mi = 0; mi < 2; ++mi)
            #pragma unroll
            for (int ni = 0; ni < 4; ++ni) {
                acc[mi][ni] = MFMA16(a[mi], bh[ni], acc[mi][ni]);
                acc[mi][ni] = MFMA16(a[mi], bl[ni], acc[mi][ni]);
            }
        __syncthreads();
        cur ^= 1;
    }

    const size_t obase = (size_t)bk * NDIM;
    #pragma unroll
    for (int mi = 0; mi < 2; ++mi) {
        #pragma unroll
        for (int r = 0; r < 4; ++r) {
            int row = m0 + wm + mi * 16 + quad * 4 + r;
            float hv = hk[obase + row];
            #pragma unroll
            for (int ni = 0; ni < 4; ++ni) {
                int col = n0 + wn + ni * 16 + l16;
                int d = col - row; d = d < -15 ? -15 : (d > 14 ? 14 : d); d += 15;
                out[(obase + row) * NDIM + col] = acc[mi][ni][r] + hv + tk[obase + col] + skr[d];
            }
        }
    }
}

// ---------------------------------------------------------------------------
extern "C" void kernel_launch(void* const* d_in, const int* in_sizes, int n_in,
                              void* d_out, int out_size, void* d_ws, size_t ws_size,
                              hipStream_t stream) {
    const float* x    = (const float*)d_in[0];
    const float* y    = (const float*)d_in[1];
    // d_in[2] = z : unused
    const float* m1w  = (const float*)d_in[3];
    const float* m1b  = (const float*)d_in[4];
    const float* m2w  = (const float*)d_in[5];
    const float* m2b  = (const float*)d_in[6];
    const float* hw   = (const float*)d_in[7];
    const float* hb   = (const float*)d_in[8];
    const float* tw   = (const float*)d_in[9];
    const float* tb   = (const float*)d_in[10];
    const float* biafW= (const float*)d_in[11];
    const float* W    = (const float*)d_in[12];
    const float* semb = (const float*)d_in[13];

    char* p = (char*)d_ws;
    float* hk   = (float*)p;                    p += 57344;
    float* tk   = (float*)p;                    p += 57344;
    float* skp  = (float*)p;                    p += 2048;
    float* headf= (float*)p;                    p += 1048576;
    float* tailf= (float*)p;                    p += 1048576;
    ushort_t* h1hi = (ushort_t*)p;              p += 589824;
    ushort_t* h1lo = (ushort_t*)p;              p += 589824;
    ushort_t* t1hi = (ushort_t*)p;              p += 589824;
    ushort_t* t1lo = (ushort_t*)p;              p += 589824;
    ushort_t* packW= (ushort_t*)p;              p += 3096576;  // 14*384*288*2
    ushort_t* whi  = (ushort_t*)p;              p += 1572864;  // 4*256*768*2
    ushort_t* wlo  = (ushort_t*)p;              p += 1572864;
    ushort_t* Abuf = (ushort_t*)p;              p += 8257536;  // 28*512*288*2
    ushort_t* xhi  = (ushort_t*)p;              p += 1572864;  // 1024*768*2
    ushort_t* xlo  = (ushort_t*)p;              p += 1572864;
    ushort_t* yhi  = (ushort_t*)p;              p += 1572864;
    ushort_t* ylo  = (ushort_t*)p;              p += 1572864;

    prep_all<<<4328, 256, 0, stream>>>(biafW, packW, x, y, m1w, m2w, hw, tw,
                                       xhi, xlo, yhi, ylo, whi, wlo,
                                       h1hi, h1lo, t1hi, t1lo);
    proj_mfma<<<512, 256, 0, stream>>>(xhi, xlo, yhi, ylo, whi, wlo,
                                       m1b, m2b, hb, tb,
                                       h1hi, h1lo, t1hi, t1lo, headf, tailf);
    mb_hk<<<802, 256, 0, stream>>>(h1hi, h1lo, packW, Abuf,
                                   headf, tailf, W, semb, hk, tk, skp);
    mo_tile<<<896, 256, 0, stream>>>(Abuf, t1hi, t1lo, hk, tk, skp,
                                     (float*)d_out);
}

// Round 7
// 177.325 us; speedup vs baseline: 1.3104x; 1.0155x over previous
//
#include <hip/hip_runtime.h>
#include <hip/hip_bf16.h>
#include <math.h>
#include <stdint.h>

#define BDIM 2
#define NDIM 512
#define HID 768
#define BIAF 256
#define CLS 14
#define DD 257   // BIAF+1
#define NPOS 30
#define SDIM 25
#define HSZ 539  // 2*257+25
#define PK 288   // padded contraction length (i and j), 9*32
#define PJ 384   // packW j-rows padding

typedef unsigned short ushort_t;
typedef __attribute__((ext_vector_type(8))) short short8;   // 8 bf16
typedef __attribute__((ext_vector_type(4))) float floatx4;  // 4 f32
typedef __attribute__((ext_vector_type(4))) unsigned short ushort4_t;

#define MFMA16(a, b, c) __builtin_amdgcn_mfma_f32_16x16x32_bf16((a), (b), (c), 0, 0, 0)

__device__ inline float bf2f(ushort_t u) {
    union { unsigned int i; float f; } c; c.i = ((unsigned)u) << 16; return c.f;
}
__device__ inline ushort_t f2bf(float f) {
    __hip_bfloat16 h = __float2bfloat16(f);
    return *(ushort_t*)&h;
}

// XCD-aware chunked swizzle (T1, bijective when nwg % 8 == 0).
__device__ inline int xcd_swz(int bid, int nwg) {
    int q = nwg >> 3;
    return (bid & 7) * q + (bid >> 3);
}

// async global->LDS, 16B per lane. LDS dest = wave-uniform base + lane*16.
__device__ inline void glds16(const ushort_t* g, const ushort_t* l) {
    __builtin_amdgcn_global_load_lds(
        (const __attribute__((address_space(1))) unsigned int*)(unsigned long long)(uintptr_t)g,
        (__attribute__((address_space(3))) unsigned int*)(unsigned int)(uintptr_t)l,
        16, 0, 0);
}

// ---------------------------------------------------------------------------
// LDS seg layout (verified R1-R6): seg = [16 rows][32 cols] bf16 (1KB);
// element (r,c) lives at byte (r>>1)*128 + ((((r&1)<<2)|(c>>3)) ^ ((r>>1)&7))*16
// + (c&7)*2.  Fragment read (l16,quad) = rbase formula (inverse-verified).
// glds path: linear dest + inverse-swizzled global source (srow/scol).
// ds_write path (prep_proj): swizzle applied on the write address directly.
// ---------------------------------------------------------------------------

// ---------------------------------------------------------------------------
// prep_proj: ONE launch, three independent block families:
//   [0..511]      proj: 4 projections, in-kernel f32->hi/lo split staging
//                 (deletes wsplit/xysplit round-trip; MFMA order == R6 ->
//                  bit-identical h1/t1/headf/tailf)
//   [512..2023]   repack biafW -> packW (linear PJxPK layout, == R6)
//   [2024..2535]  h1/t1 pad columns (== R6)
// ---------------------------------------------------------------------------
__global__ __launch_bounds__(256) void prep_proj(
    const float* __restrict__ x, const float* __restrict__ y,
    const float* __restrict__ m1w, const float* __restrict__ m2w,
    const float* __restrict__ hw,  const float* __restrict__ tw,
    const float* __restrict__ m1b, const float* __restrict__ m2b,
    const float* __restrict__ hb,  const float* __restrict__ tb,
    const float* __restrict__ biafW, ushort_t* __restrict__ packW,
    ushort_t* __restrict__ h1hi, ushort_t* __restrict__ h1lo,
    ushort_t* __restrict__ t1hi, ushort_t* __restrict__ t1lo,
    float* __restrict__ headf, float* __restrict__ tailf)
{
    __shared__ __align__(16) ushort_t Sh[2 * 6144];   // 24 KB (dbuf 12KB)
    const int bid = blockIdx.x;
    const int tid = threadIdx.x;

    if (bid >= 2024) {
        // ---- pads: h1/t1 cols 256..287; col 256 = 1.0 on hi planes ----
        int idx = (bid - 2024) * 256 + tid;    // 0..131071
        int plane = idx >> 15;
        int tok = (idx >> 5) & 1023;
        int c   = 256 + (idx & 31);
        ushort_t* dst = (plane == 0) ? h1hi : (plane == 1) ? h1lo : (plane == 2) ? t1hi : t1lo;
        ushort_t val = (c == 256 && (plane == 0 || plane == 2)) ? (ushort_t)0x3F80 : (ushort_t)0;
        dst[(size_t)tok * PK + c] = val;
        return;
    }
    if (bid >= 512) {
        // ---- repack biafW[k][i][j] -> packW[k][j][i], zero-padded ----
        float (*tile)[33] = reinterpret_cast<float(*)[33]>(Sh);
        const int rb = bid - 512;
        const int ix = rb % 9;
        const int jy = (rb / 9) % 12;
        const int k  = rb / 108;
        const int i0 = ix * 32, j0 = jy * 32;
        const int r8 = tid >> 5;
        const int c  = tid & 31;
        #pragma unroll
        for (int rr = 0; rr < 4; ++rr) {
            int r = rr * 8 + r8;
            int gi = i0 + r, gj = j0 + c;
            tile[r][c] = (gi < DD && gj < DD) ? biafW[((size_t)k * DD + gi) * DD + gj] : 0.f;
        }
        __syncthreads();
        #pragma unroll
        for (int rr = 0; rr < 4; ++rr) {
            int jr = rr * 8 + r8;
            packW[((size_t)k * PJ + (j0 + jr)) * PK + i0 + c] = f2bf(tile[c][jr]);
        }
        return;
    }

    // ---- proj: block = 64 tok x 32 feat, 24 k-steps, dbuf in-kernel split ----
    const int flat = xcd_swz(bid, 512);
    const int ft = flat & 7;
    const int mt = (flat >> 3) & 15;
    const int proj = flat >> 7;
    const int wave = tid >> 6, L = tid & 63;
    const int quad = L >> 4, l16 = L & 15;
    const int rbase = (l16 >> 1) * 64 + (((((l16 & 1) << 2) | quad) ^ (l16 >> 1)) * 8);
    const int tok0 = mt * 64 + wave * 16;
    const int f0 = ft * 32;

    // write-side swizzle for A staging: lane -> (row ar, col-quad acq) of its
    // wave's 16x32 seg
    const int ar = L >> 2, acq = L & 3;
    const int aoffe = ((ar >> 1) * 64) + (((((ar & 1) << 2) | acq) ^ ((ar >> 1) & 7)) * 8);
    // write-side for W staging: thread -> (feat row fr, col wc4) of 32x32 tile
    const int fr = tid >> 3, wc4 = (tid & 7) * 4;
    const int wseg = fr >> 4, wr = fr & 15;
    const int woffe = ((wr >> 1) * 64) + (((((wr & 1) << 2) | (wc4 >> 3)) ^ ((wr >> 1) & 7)) * 8) + (wc4 & 7);

    const float* asrc = (proj == 1) ? y : x;
    const float* wsrc = (proj == 0) ? m1w : (proj == 1) ? m2w : (proj == 2) ? hw : tw;
    const float* bias = (proj == 0) ? m1b : (proj == 1) ? m2b : (proj == 2) ? hb : tb;
    const float* aptr = asrc + (size_t)(mt * 64 + wave * 16 + ar) * HID + acq * 8;
    const float* wptr = wsrc + (size_t)(f0 + fr) * HID + wc4;

    auto cvt_write = [&](int bo, float4 a0, float4 a1, float4 wv) {
        ushort_t* B = Sh + bo * 6144;
        float av[8] = {a0.x, a0.y, a0.z, a0.w, a1.x, a1.y, a1.z, a1.w};
        short8 hh, ll;
        #pragma unroll
        for (int j = 0; j < 8; ++j) {
            ushort_t h = f2bf(av[j]);
            hh[j] = (short)h;
            ll[j] = (short)f2bf(av[j] - bf2f(h));
        }
        *(short8*)(B + wave * 512 + aoffe) = hh;           // Ah seg[wave]
        *(short8*)(B + 2048 + wave * 512 + aoffe) = ll;    // Al seg[wave]
        float wvv[4] = {wv.x, wv.y, wv.z, wv.w};
        ushort4_t wh, wl;
        #pragma unroll
        for (int j = 0; j < 4; ++j) {
            ushort_t h = f2bf(wvv[j]);
            wh[j] = h;
            wl[j] = f2bf(wvv[j] - bf2f(h));
        }
        *(ushort4_t*)(B + 4096 + wseg * 512 + woffe) = wh; // Wh segs
        *(ushort4_t*)(B + 5120 + wseg * 512 + woffe) = wl; // Wl segs
    };

    floatx4 acc0 = {0.f, 0.f, 0.f, 0.f}, acc1 = {0.f, 0.f, 0.f, 0.f};

    // prologue: stage step 0, preload step 1
    float4 pa0 = *(const float4*)(aptr);
    float4 pa1 = *(const float4*)(aptr + 4);
    float4 pw  = *(const float4*)(wptr);
    cvt_write(0, pa0, pa1, pw);
    pa0 = *(const float4*)(aptr + 32);
    pa1 = *(const float4*)(aptr + 36);
    pw  = *(const float4*)(wptr + 32);
    __syncthreads();

    int cur = 0;
    #pragma unroll 2
    for (int t = 0; t < 24; ++t) {
        if (t < 23) {
            cvt_write(cur ^ 1, pa0, pa1, pw);   // stage t+1 into other buffer
            if (t < 22) {
                int k2 = (t + 2) * 32;
                pa0 = *(const float4*)(aptr + k2);
                pa1 = *(const float4*)(aptr + k2 + 4);
                pw  = *(const float4*)(wptr + k2);
            }
        }
        const ushort_t* B = Sh + cur * 6144;
        short8 ah  = *(const short8*)(B + wave * 512 + rbase);
        short8 al  = *(const short8*)(B + 2048 + wave * 512 + rbase);
        short8 bh0 = *(const short8*)(B + 4096 + rbase);
        short8 bh1 = *(const short8*)(B + 4608 + rbase);
        short8 bl0 = *(const short8*)(B + 5120 + rbase);
        short8 bl1 = *(const short8*)(B + 5632 + rbase);
        acc0 = MFMA16(ah, bh0, acc0);
        acc1 = MFMA16(ah, bh1, acc1);
        acc0 = MFMA16(al, bh0, acc0);
        acc1 = MFMA16(al, bh1, acc1);
        acc0 = MFMA16(ah, bl0, acc0);
        acc1 = MFMA16(ah, bl1, acc1);
        __syncthreads();
        cur ^= 1;
    }

    #pragma unroll
    for (int nf = 0; nf < 2; ++nf) {
        floatx4 a = nf ? acc1 : acc0;
        int feat = f0 + nf * 16 + l16;
        float bv = bias[feat];
        #pragma unroll
        for (int r = 0; r < 4; ++r) {
            int tok = tok0 + quad * 4 + r;
            float v = a[r] + bv;
            if (proj <= 1) {
                float g = 0.5f * v * (1.0f + erff(v * 0.70710678118654752f));
                ushort_t h = f2bf(g);
                ushort_t lo = f2bf(g - bf2f(h));
                if (proj == 0) { h1hi[(size_t)tok * PK + feat] = h; h1lo[(size_t)tok * PK + feat] = lo; }
                else           { t1hi[(size_t)tok * PK + feat] = h; t1lo[(size_t)tok * PK + feat] = lo; }
            } else {
                float lv = (v >= 0.f) ? v : 0.01f * v;
                if (proj == 2) headf[(size_t)tok * 256 + feat] = lv;
                else           tailf[(size_t)tok * 256 + feat] = lv;
            }
        }
    }
}

// ---------------------------------------------------------------------------
// mb_hk: fused mb_tile (blocks 0..671, XCD-swizzled) + hk_tk_sk (672..801).
// (verbatim R6)
// ---------------------------------------------------------------------------
__global__ __launch_bounds__(256) void mb_hk(
    const ushort_t* __restrict__ h1hi, const ushort_t* __restrict__ h1lo,
    const ushort_t* __restrict__ packW,
    ushort_t* __restrict__ Ab,
    const float* __restrict__ headf, const float* __restrict__ tailf,
    const float* __restrict__ W, const float* __restrict__ semb,
    float* __restrict__ hk, float* __restrict__ tk, float* __restrict__ skp)
{
    const int bid = blockIdx.x;
    if (bid >= 672) {
        const int hb = bid - 672;           // 0..129
        if (hb >= 128) {
            int idx = (hb - 128) * 256 + threadIdx.x;
            if (idx < CLS * NPOS) {
                int k = idx / NPOS, d = idx % NPOS;
                float acc = 0.f;
                for (int h = 0; h < SDIM; ++h)
                    acc += semb[d*SDIM + h] * W[k*HSZ + 2*DD + h];
                skp[idx] = acc;
            }
            return;
        }
        int p = hb * 256 + threadIdx.x;      // 32768 items
        int which = p >> 14;                 // 0=hk, 1=tk
        int idx = p & 16383;
        int tok = idx >> 4;
        int k = idx & 15;
        if (k >= CLS) return;
        const float* row = (which ? tailf : headf) + (size_t)tok * 256;
        const float* wr = W + (size_t)k * HSZ + (which ? DD : 0);
        float acc = 0.f;
        for (int f4 = 0; f4 < 64; ++f4) {
            float4 rv = *(const float4*)(row + f4 * 4);
            acc += rv.x * wr[f4*4] + rv.y * wr[f4*4+1] + rv.z * wr[f4*4+2] + rv.w * wr[f4*4+3];
        }
        acc += wr[256];
        float* dst = which ? tk : hk;
        dst[(size_t)(tok >> 9) * CLS * NDIM + (size_t)k * NDIM + (tok & 511)] = acc;
        return;
    }

    // ---- mb_tile, double-buffered, XCD-swizzled ----
    __shared__ ushort_t Ah[2 * 2048];   // 2 x 4KB
    __shared__ ushort_t Al[2 * 2048];   // 2 x 4KB
    __shared__ ushort_t Bt[2 * 3072];   // 2 x 6KB
    const int flat = xcd_swz(bid, 672);
    const int jt = flat % 3, mt = (flat / 3) % 8, bk = flat / 24;
    const int b = bk / CLS, k = bk % CLS;
    const int tid = threadIdx.x;
    const int wave = tid >> 6, L = tid & 63;
    const int quad = L >> 4, l16 = L & 15;
    const int sr = L >> 3, u = (L & 7) ^ sr;
    const int srow = 2 * sr + (u >> 2);        // row within 16-row segment
    const int scol = (u & 3) * 8;              // element col within 32
    const int rbase = (l16 >> 1) * 64 + ((((((l16 & 1) << 2) | quad)) ^ (l16 >> 1)) * 8);
    const int m0 = mt * 64, j0 = jt * 96;
    const int wm = (wave >> 1) * 32, wj = (wave & 1) * 48;

    const ushort_t* gAh = h1hi + (size_t)(b * NDIM + m0) * PK;
    const ushort_t* gAl = h1lo + (size_t)(b * NDIM + m0) * PK;
    const ushort_t* gB  = packW + ((size_t)k * PJ + j0) * PK;

    auto stage = [&](int bo, int k0) {
        for (int s = wave; s < 14; s += 4) {
            const ushort_t* g; const ushort_t* l;
            if (s < 4)      { l = Ah + bo * 2048 + s * 512;       g = gAh + (size_t)(s * 16 + srow) * PK + k0 + scol; }
            else if (s < 8) { l = Al + bo * 2048 + (s - 4) * 512; g = gAl + (size_t)((s - 4) * 16 + srow) * PK + k0 + scol; }
            else            { l = Bt + bo * 3072 + (s - 8) * 512; g = gB  + (size_t)((s - 8) * 16 + srow) * PK + k0 + scol; }
            glds16(g, l);
        }
    };

    floatx4 acc[2][3];
    #pragma unroll
    for (int mi = 0; mi < 2; ++mi)
        #pragma unroll
        for (int ni = 0; ni < 3; ++ni)
            #pragma unroll
            for (int r = 0; r < 4; ++r) acc[mi][ni][r] = 0.f;

    stage(0, 0);
    __syncthreads();
    int cur = 0;
    for (int t = 0; t < 9; ++t) {
        if (t < 8) stage(cur ^ 1, (t + 1) * 32);   // prefetch next tile
        short8 ah[2], al[2], bb[3];
        #pragma unroll
        for (int mi = 0; mi < 2; ++mi) {
            ah[mi] = *(const short8*)(Ah + cur * 2048 + (wm + mi * 16) * 32 + rbase);
            al[mi] = *(const short8*)(Al + cur * 2048 + (wm + mi * 16) * 32 + rbase);
        }
        #pragma unroll
        for (int ni = 0; ni < 3; ++ni)
            bb[ni] = *(const short8*)(Bt + cur * 3072 + (wj + ni * 16) * 32 + rbase);
        #pragma unroll
        for (int mi = 0; mi < 2; ++mi)
            #pragma unroll
            for (int ni = 0; ni < 3; ++ni) {
                acc[mi][ni] = MFMA16(ah[mi], bb[ni], acc[mi][ni]);
                acc[mi][ni] = MFMA16(al[mi], bb[ni], acc[mi][ni]);
            }
        __syncthreads();
        cur ^= 1;
    }

    ushort_t* Aout = Ab + (size_t)bk * NDIM * PK;
    #pragma unroll
    for (int mi = 0; mi < 2; ++mi) {
        #pragma unroll
        for (int r = 0; r < 4; ++r) {
            int row = m0 + wm + mi * 16 + quad * 4 + r;
            #pragma unroll
            for (int ni = 0; ni < 3; ++ni) {
                int col = j0 + wj + ni * 16 + l16;
                Aout[(size_t)row * PK + col] = f2bf(acc[mi][ni][r]);
            }
        }
    }
}

// ---------------------------------------------------------------------------
// mo_tile: out[bk][m][n] = sum_j A[bk][m][j]*t1[b][n][j] + hk + tk + sk
// (verbatim R6)
// ---------------------------------------------------------------------------
__global__ __launch_bounds__(256) void mo_tile(
    const ushort_t* __restrict__ Ab,
    const ushort_t* __restrict__ t1hi, const ushort_t* __restrict__ t1lo,
    const float* __restrict__ hk, const float* __restrict__ tk,
    const float* __restrict__ sk,
    float* __restrict__ out)
{
    __shared__ ushort_t At[2 * 2048];    // 2 x 4KB
    __shared__ ushort_t Bh[2 * 4096];    // 2 x 8KB
    __shared__ ushort_t Bl[2 * 4096];    // 2 x 8KB
    __shared__ float skr[NPOS];
    const int flat = xcd_swz(blockIdx.x, 896);
    const int nt = flat & 3, mt = (flat >> 2) & 7, bk = flat >> 5;
    const int b = bk / CLS, k = bk % CLS;
    const int tid = threadIdx.x;
    if (tid < NPOS) skr[tid] = sk[k * NPOS + tid];
    const int wave = tid >> 6, L = tid & 63;
    const int quad = L >> 4, l16 = L & 15;
    const int sr = L >> 3, u = (L & 7) ^ sr;
    const int srow = 2 * sr + (u >> 2);
    const int scol = (u & 3) * 8;
    const int rbase = (l16 >> 1) * 64 + ((((((l16 & 1) << 2) | quad)) ^ (l16 >> 1)) * 8);
    const int m0 = mt * 64, n0 = nt * 128;
    const int wm = (wave >> 1) * 32, wn = (wave & 1) * 64;

    const ushort_t* gA  = Ab + ((size_t)bk * NDIM + m0) * PK;
    const ushort_t* gBh = t1hi + (size_t)(b * NDIM + n0) * PK;
    const ushort_t* gBl = t1lo + (size_t)(b * NDIM + n0) * PK;

    auto stage = [&](int bo, int k0) {
        for (int s = wave; s < 20; s += 4) {
            const ushort_t* g; const ushort_t* l;
            if (s < 4)       { l = At + bo * 2048 + s * 512;         g = gA  + (size_t)(s * 16 + srow) * PK + k0 + scol; }
            else if (s < 12) { l = Bh + bo * 4096 + (s - 4) * 512;   g = gBh + (size_t)((s - 4) * 16 + srow) * PK + k0 + scol; }
            else             { l = Bl + bo * 4096 + (s - 12) * 512;  g = gBl + (size_t)((s - 12) * 16 + srow) * PK + k0 + scol; }
            glds16(g, l);
        }
    };

    floatx4 acc[2][4];
    #pragma unroll
    for (int mi = 0; mi < 2; ++mi)
        #pragma unroll
        for (int ni = 0; ni < 4; ++ni)
            #pragma unroll
            for (int r = 0; r < 4; ++r) acc[mi][ni][r] = 0.f;

    stage(0, 0);
    __syncthreads();
    int cur = 0;
    for (int t = 0; t < 9; ++t) {
        if (t < 8) stage(cur ^ 1, (t + 1) * 32);   // prefetch next tile
        short8 a[2], bh[4], bl[4];
        #pragma unroll
        for (int mi = 0; mi < 2; ++mi)
            a[mi] = *(const short8*)(At + cur * 2048 + (wm + mi * 16) * 32 + rbase);
        #pragma unroll
        for (int ni = 0; ni < 4; ++ni) {
            bh[ni] = *(const short8*)(Bh + cur * 4096 + (wn + ni * 16) * 32 + rbase);
            bl[ni] = *(const short8*)(Bl + cur * 4096 + (wn + ni * 16) * 32 + rbase);
        }
        #pragma unroll
        for (int mi = 0; mi < 2; ++mi)
            #pragma unroll
            for (int ni = 0; ni < 4; ++ni) {
                acc[mi][ni] = MFMA16(a[mi], bh[ni], acc[mi][ni]);
                acc[mi][ni] = MFMA16(a[mi], bl[ni], acc[mi][ni]);
            }
        __syncthreads();
        cur ^= 1;
    }

    const size_t obase = (size_t)bk * NDIM;
    #pragma unroll
    for (int mi = 0; mi < 2; ++mi) {
        #pragma unroll
        for (int r = 0; r < 4; ++r) {
            int row = m0 + wm + mi * 16 + quad * 4 + r;
            float hv = hk[obase + row];
            #pragma unroll
            for (int ni = 0; ni < 4; ++ni) {
                int col = n0 + wn + ni * 16 + l16;
                int d = col - row; d = d < -15 ? -15 : (d > 14 ? 14 : d); d += 15;
                out[(obase + row) * NDIM + col] = acc[mi][ni][r] + hv + tk[obase + col] + skr[d];
            }
        }
    }
}

// ---------------------------------------------------------------------------
extern "C" void kernel_launch(void* const* d_in, const int* in_sizes, int n_in,
                              void* d_out, int out_size, void* d_ws, size_t ws_size,
                              hipStream_t stream) {
    const float* x    = (const float*)d_in[0];
    const float* y    = (const float*)d_in[1];
    // d_in[2] = z : unused
    const float* m1w  = (const float*)d_in[3];
    const float* m1b  = (const float*)d_in[4];
    const float* m2w  = (const float*)d_in[5];
    const float* m2b  = (const float*)d_in[6];
    const float* hw   = (const float*)d_in[7];
    const float* hb   = (const float*)d_in[8];
    const float* tw   = (const float*)d_in[9];
    const float* tb   = (const float*)d_in[10];
    const float* biafW= (const float*)d_in[11];
    const float* W    = (const float*)d_in[12];
    const float* semb = (const float*)d_in[13];

    char* p = (char*)d_ws;
    float* hk   = (float*)p;                    p += 57344;
    float* tk   = (float*)p;                    p += 57344;
    float* skp  = (float*)p;                    p += 2048;
    float* headf= (float*)p;                    p += 1048576;
    float* tailf= (float*)p;                    p += 1048576;
    ushort_t* h1hi = (ushort_t*)p;              p += 589824;
    ushort_t* h1lo = (ushort_t*)p;              p += 589824;
    ushort_t* t1hi = (ushort_t*)p;              p += 589824;
    ushort_t* t1lo = (ushort_t*)p;              p += 589824;
    ushort_t* packW= (ushort_t*)p;              p += 3096576;  // 14*384*288*2
    ushort_t* Abuf = (ushort_t*)p;              p += 8257536;  // 28*512*288*2

    prep_proj<<<2536, 256, 0, stream>>>(x, y, m1w, m2w, hw, tw,
                                        m1b, m2b, hb, tb,
                                        biafW, packW,
                                        h1hi, h1lo, t1hi, t1lo, headf, tailf);
    mb_hk<<<802, 256, 0, stream>>>(h1hi, h1lo, packW, Abuf,
                                   headf, tailf, W, semb, hk, tk, skp);
    mo_tile<<<896, 256, 0, stream>>>(Abuf, t1hi, t1lo, hk, tk, skp,
                                     (float*)d_out);
}

// Round 8
// 176.436 us; speedup vs baseline: 1.3170x; 1.0050x over previous
//
#include <hip/hip_runtime.h>
#include <hip/hip_bf16.h>
#include <math.h>
#include <stdint.h>

#define BDIM 2
#define NDIM 512
#define HID 768
#define BIAF 256
#define CLS 14
#define DD 257   // BIAF+1
#define NPOS 30
#define SDIM 25
#define HSZ 539  // 2*257+25
#define PK 288   // padded contraction length (i and j), 9*32
#define PJ 384   // packW j-rows padding

typedef unsigned short ushort_t;
typedef __attribute__((ext_vector_type(8))) short short8;   // 8 bf16
typedef __attribute__((ext_vector_type(4))) float floatx4;  // 4 f32
typedef __attribute__((ext_vector_type(4))) unsigned short ushort4_t;

#define MFMA16(a, b, c) __builtin_amdgcn_mfma_f32_16x16x32_bf16((a), (b), (c), 0, 0, 0)

__device__ inline float bf2f(ushort_t u) {
    union { unsigned int i; float f; } c; c.i = ((unsigned)u) << 16; return c.f;
}
__device__ inline ushort_t f2bf(float f) {
    __hip_bfloat16 h = __float2bfloat16(f);
    return *(ushort_t*)&h;
}

// XCD-aware chunked swizzle (T1, bijective when nwg % 8 == 0).
__device__ inline int xcd_swz(int bid, int nwg) {
    int q = nwg >> 3;
    return (bid & 7) * q + (bid >> 3);
}

// async global->LDS, 16B per lane. LDS dest = wave-uniform base + lane*16.
__device__ inline void glds16(const ushort_t* g, const ushort_t* l) {
    __builtin_amdgcn_global_load_lds(
        (const __attribute__((address_space(1))) unsigned int*)(unsigned long long)(uintptr_t)g,
        (__attribute__((address_space(3))) unsigned int*)(unsigned int)(uintptr_t)l,
        16, 0, 0);
}

// ---------------------------------------------------------------------------
// LDS seg layout (verified R1-R7): seg = [16 rows][32 cols] bf16 (1KB);
// element (r,c) at elem-off (r>>1)*64 + ((((r&1)<<2)|(c>>3)) ^ ((r>>1)&7))*8
// + (c&7).  Fragment read (l16,quad) = rbase.  glds path: linear dest +
// inverse-swizzled source.  ds_write path: swizzle applied on write address.
// ---------------------------------------------------------------------------

// ---------------------------------------------------------------------------
// prep_proj v2: ONE launch, three block families:
//   [0..1023]     proj: 32tok x 32feat blocks (4 blocks/CU -> TLP hides the
//                 per-step load latency that bounded the 512-block version),
//                 in-kernel f32->hi/lo split staging, 24 dbuf k-steps.
//                 MFMA chain per output identical -> bit-identical.
//   [1024..2535]  repack biafW -> packW (linear PJxPK, verbatim)
//   [2536..3047]  h1/t1 pad columns (verbatim)
// ---------------------------------------------------------------------------
__global__ __launch_bounds__(256) void prep_proj(
    const float* __restrict__ x, const float* __restrict__ y,
    const float* __restrict__ m1w, const float* __restrict__ m2w,
    const float* __restrict__ hw,  const float* __restrict__ tw,
    const float* __restrict__ m1b, const float* __restrict__ m2b,
    const float* __restrict__ hb,  const float* __restrict__ tb,
    const float* __restrict__ biafW, ushort_t* __restrict__ packW,
    ushort_t* __restrict__ h1hi, ushort_t* __restrict__ h1lo,
    ushort_t* __restrict__ t1hi, ushort_t* __restrict__ t1lo,
    float* __restrict__ headf, float* __restrict__ tailf)
{
    __shared__ __align__(16) ushort_t Sh[2 * 4096];   // 16 KB (dbuf 8KB)
    const int bid = blockIdx.x;
    const int tid = threadIdx.x;

    if (bid >= 2536) {
        // ---- pads: h1/t1 cols 256..287; col 256 = 1.0 on hi planes ----
        int idx = (bid - 2536) * 256 + tid;    // 0..131071
        int plane = idx >> 15;
        int tok = (idx >> 5) & 1023;
        int c   = 256 + (idx & 31);
        ushort_t* dst = (plane == 0) ? h1hi : (plane == 1) ? h1lo : (plane == 2) ? t1hi : t1lo;
        ushort_t val = (c == 256 && (plane == 0 || plane == 2)) ? (ushort_t)0x3F80 : (ushort_t)0;
        dst[(size_t)tok * PK + c] = val;
        return;
    }
    if (bid >= 1024) {
        // ---- repack biafW[k][i][j] -> packW[k][j][i], zero-padded ----
        float (*tile)[33] = reinterpret_cast<float(*)[33]>(Sh);
        const int rb = bid - 1024;
        const int ix = rb % 9;
        const int jy = (rb / 9) % 12;
        const int k  = rb / 108;
        const int i0 = ix * 32, j0 = jy * 32;
        const int r8 = tid >> 5;
        const int c  = tid & 31;
        #pragma unroll
        for (int rr = 0; rr < 4; ++rr) {
            int r = rr * 8 + r8;
            int gi = i0 + r, gj = j0 + c;
            tile[r][c] = (gi < DD && gj < DD) ? biafW[((size_t)k * DD + gi) * DD + gj] : 0.f;
        }
        __syncthreads();
        #pragma unroll
        for (int rr = 0; rr < 4; ++rr) {
            int jr = rr * 8 + r8;
            packW[((size_t)k * PJ + (j0 + jr)) * PK + i0 + c] = f2bf(tile[c][jr]);
        }
        return;
    }

    // ---- proj: block = 32 tok x 32 feat, 24 k-steps, dbuf in-kernel split ----
    const int flat = xcd_swz(bid, 1024);
    const int ft  = flat & 7;          // 8  -> 32 feats
    const int mt2 = (flat >> 3) & 31;  // 32 -> 32 tokens
    const int proj = flat >> 8;        // 4
    const int wave = tid >> 6, L = tid & 63;
    const int quad = L >> 4, l16 = L & 15;
    const int mi = wave >> 1, fi = wave & 1;   // wave -> (16-tok frag, 16-feat frag)
    const int rbase = (l16 >> 1) * 64 + (((((l16 & 1) << 2) | quad) ^ (l16 >> 1)) * 8);

    // staging: thread -> (row srw 0..31, col-quad sc4 0..7) of the 32x32 step
    const int srw = tid >> 3, sc4 = tid & 7;
    const int sA = srw >> 4, rr = srw & 15;
    const int woffe = ((rr >> 1) * 64)
                    + (((((rr & 1) << 2) | (sc4 >> 1)) ^ ((rr >> 1) & 7)) * 8)
                    + (sc4 & 1) * 4;
    const int segA = sA * 512 + woffe;

    const float* asrc = (proj == 1) ? y : x;
    const float* wsrc = (proj == 0) ? m1w : (proj == 1) ? m2w : (proj == 2) ? hw : tw;
    const float* bias = (proj == 0) ? m1b : (proj == 1) ? m2b : (proj == 2) ? hb : tb;
    const float* aptr = asrc + (size_t)(mt2 * 32 + srw) * HID + sc4 * 4;
    const float* wptr = wsrc + (size_t)(ft * 32 + srw) * HID + sc4 * 4;

    auto cvt_write = [&](int bo, float4 av, float4 wv) {
        ushort_t* B = Sh + bo * 4096;
        float aa[4] = {av.x, av.y, av.z, av.w};
        ushort4_t ah, al;
        #pragma unroll
        for (int j = 0; j < 4; ++j) {
            ushort_t h = f2bf(aa[j]);
            ah[j] = h;
            al[j] = f2bf(aa[j] - bf2f(h));
        }
        *(ushort4_t*)(B + segA) = ah;           // Ah segs [0,1]
        *(ushort4_t*)(B + 1024 + segA) = al;    // Al segs [2,3]
        float ww[4] = {wv.x, wv.y, wv.z, wv.w};
        ushort4_t wh, wl;
        #pragma unroll
        for (int j = 0; j < 4; ++j) {
            ushort_t h = f2bf(ww[j]);
            wh[j] = h;
            wl[j] = f2bf(ww[j] - bf2f(h));
        }
        *(ushort4_t*)(B + 2048 + segA) = wh;    // Wh segs [4,5]
        *(ushort4_t*)(B + 3072 + segA) = wl;    // Wl segs [6,7]
    };

    floatx4 acc = {0.f, 0.f, 0.f, 0.f};

    // prologue: stage step 0, preload step 1
    float4 pa = *(const float4*)(aptr);
    float4 pw = *(const float4*)(wptr);
    cvt_write(0, pa, pw);
    pa = *(const float4*)(aptr + 32);
    pw = *(const float4*)(wptr + 32);
    __syncthreads();

    int cur = 0;
    #pragma unroll 2
    for (int t = 0; t < 24; ++t) {
        if (t < 23) {
            cvt_write(cur ^ 1, pa, pw);   // stage t+1 into other buffer
            if (t < 22) {
                int k2 = (t + 2) * 32;
                pa = *(const float4*)(aptr + k2);
                pw = *(const float4*)(wptr + k2);
            }
        }
        const ushort_t* B = Sh + cur * 4096;
        short8 ah = *(const short8*)(B + mi * 512 + rbase);
        short8 al = *(const short8*)(B + 1024 + mi * 512 + rbase);
        short8 bh = *(const short8*)(B + 2048 + fi * 512 + rbase);
        short8 bl = *(const short8*)(B + 3072 + fi * 512 + rbase);
        acc = MFMA16(ah, bh, acc);
        acc = MFMA16(al, bh, acc);
        acc = MFMA16(ah, bl, acc);
        __syncthreads();
        cur ^= 1;
    }

    {
        int feat = ft * 32 + fi * 16 + l16;
        float bv = bias[feat];
        #pragma unroll
        for (int r = 0; r < 4; ++r) {
            int tok = mt2 * 32 + mi * 16 + quad * 4 + r;
            float v = acc[r] + bv;
            if (proj <= 1) {
                float g = 0.5f * v * (1.0f + erff(v * 0.70710678118654752f));
                ushort_t h = f2bf(g);
                ushort_t lo = f2bf(g - bf2f(h));
                if (proj == 0) { h1hi[(size_t)tok * PK + feat] = h; h1lo[(size_t)tok * PK + feat] = lo; }
                else           { t1hi[(size_t)tok * PK + feat] = h; t1lo[(size_t)tok * PK + feat] = lo; }
            } else {
                float lv = (v >= 0.f) ? v : 0.01f * v;
                if (proj == 2) headf[(size_t)tok * 256 + feat] = lv;
                else           tailf[(size_t)tok * 256 + feat] = lv;
            }
        }
    }
}

// ---------------------------------------------------------------------------
// mb_hk: fused mb_tile (blocks 0..671, XCD-swizzled) + hk_tk_sk (672..801).
// (verbatim R6/R7)
// ---------------------------------------------------------------------------
__global__ __launch_bounds__(256) void mb_hk(
    const ushort_t* __restrict__ h1hi, const ushort_t* __restrict__ h1lo,
    const ushort_t* __restrict__ packW,
    ushort_t* __restrict__ Ab,
    const float* __restrict__ headf, const float* __restrict__ tailf,
    const float* __restrict__ W, const float* __restrict__ semb,
    float* __restrict__ hk, float* __restrict__ tk, float* __restrict__ skp)
{
    const int bid = blockIdx.x;
    if (bid >= 672) {
        const int hb = bid - 672;           // 0..129
        if (hb >= 128) {
            int idx = (hb - 128) * 256 + threadIdx.x;
            if (idx < CLS * NPOS) {
                int k = idx / NPOS, d = idx % NPOS;
                float acc = 0.f;
                for (int h = 0; h < SDIM; ++h)
                    acc += semb[d*SDIM + h] * W[k*HSZ + 2*DD + h];
                skp[idx] = acc;
            }
            return;
        }
        int p = hb * 256 + threadIdx.x;      // 32768 items
        int which = p >> 14;                 // 0=hk, 1=tk
        int idx = p & 16383;
        int tok = idx >> 4;
        int k = idx & 15;
        if (k >= CLS) return;
        const float* row = (which ? tailf : headf) + (size_t)tok * 256;
        const float* wr = W + (size_t)k * HSZ + (which ? DD : 0);
        float acc = 0.f;
        for (int f4 = 0; f4 < 64; ++f4) {
            float4 rv = *(const float4*)(row + f4 * 4);
            acc += rv.x * wr[f4*4] + rv.y * wr[f4*4+1] + rv.z * wr[f4*4+2] + rv.w * wr[f4*4+3];
        }
        acc += wr[256];
        float* dst = which ? tk : hk;
        dst[(size_t)(tok >> 9) * CLS * NDIM + (size_t)k * NDIM + (tok & 511)] = acc;
        return;
    }

    // ---- mb_tile, double-buffered, XCD-swizzled ----
    __shared__ ushort_t Ah[2 * 2048];   // 2 x 4KB
    __shared__ ushort_t Al[2 * 2048];   // 2 x 4KB
    __shared__ ushort_t Bt[2 * 3072];   // 2 x 6KB
    const int flat = xcd_swz(bid, 672);
    const int jt = flat % 3, mt = (flat / 3) % 8, bk = flat / 24;
    const int b = bk / CLS, k = bk % CLS;
    const int tid = threadIdx.x;
    const int wave = tid >> 6, L = tid & 63;
    const int quad = L >> 4, l16 = L & 15;
    const int sr = L >> 3, u = (L & 7) ^ sr;
    const int srow = 2 * sr + (u >> 2);        // row within 16-row segment
    const int scol = (u & 3) * 8;              // element col within 32
    const int rbase = (l16 >> 1) * 64 + ((((((l16 & 1) << 2) | quad)) ^ (l16 >> 1)) * 8);
    const int m0 = mt * 64, j0 = jt * 96;
    const int wm = (wave >> 1) * 32, wj = (wave & 1) * 48;

    const ushort_t* gAh = h1hi + (size_t)(b * NDIM + m0) * PK;
    const ushort_t* gAl = h1lo + (size_t)(b * NDIM + m0) * PK;
    const ushort_t* gB  = packW + ((size_t)k * PJ + j0) * PK;

    auto stage = [&](int bo, int k0) {
        for (int s = wave; s < 14; s += 4) {
            const ushort_t* g; const ushort_t* l;
            if (s < 4)      { l = Ah + bo * 2048 + s * 512;       g = gAh + (size_t)(s * 16 + srow) * PK + k0 + scol; }
            else if (s < 8) { l = Al + bo * 2048 + (s - 4) * 512; g = gAl + (size_t)((s - 4) * 16 + srow) * PK + k0 + scol; }
            else            { l = Bt + bo * 3072 + (s - 8) * 512; g = gB  + (size_t)((s - 8) * 16 + srow) * PK + k0 + scol; }
            glds16(g, l);
        }
    };

    floatx4 acc[2][3];
    #pragma unroll
    for (int mi = 0; mi < 2; ++mi)
        #pragma unroll
        for (int ni = 0; ni < 3; ++ni)
            #pragma unroll
            for (int r = 0; r < 4; ++r) acc[mi][ni][r] = 0.f;

    stage(0, 0);
    __syncthreads();
    int cur = 0;
    for (int t = 0; t < 9; ++t) {
        if (t < 8) stage(cur ^ 1, (t + 1) * 32);   // prefetch next tile
        short8 ah[2], al[2], bb[3];
        #pragma unroll
        for (int mi = 0; mi < 2; ++mi) {
            ah[mi] = *(const short8*)(Ah + cur * 2048 + (wm + mi * 16) * 32 + rbase);
            al[mi] = *(const short8*)(Al + cur * 2048 + (wm + mi * 16) * 32 + rbase);
        }
        #pragma unroll
        for (int ni = 0; ni < 3; ++ni)
            bb[ni] = *(const short8*)(Bt + cur * 3072 + (wj + ni * 16) * 32 + rbase);
        #pragma unroll
        for (int mi = 0; mi < 2; ++mi)
            #pragma unroll
            for (int ni = 0; ni < 3; ++ni) {
                acc[mi][ni] = MFMA16(ah[mi], bb[ni], acc[mi][ni]);
                acc[mi][ni] = MFMA16(al[mi], bb[ni], acc[mi][ni]);
            }
        __syncthreads();
        cur ^= 1;
    }

    ushort_t* Aout = Ab + (size_t)bk * NDIM * PK;
    #pragma unroll
    for (int mi = 0; mi < 2; ++mi) {
        #pragma unroll
        for (int r = 0; r < 4; ++r) {
            int row = m0 + wm + mi * 16 + quad * 4 + r;
            #pragma unroll
            for (int ni = 0; ni < 3; ++ni) {
                int col = j0 + wj + ni * 16 + l16;
                Aout[(size_t)row * PK + col] = f2bf(acc[mi][ni][r]);
            }
        }
    }
}

// ---------------------------------------------------------------------------
// mo_tile: out[bk][m][n] = sum_j A[bk][m][j]*t1[b][n][j] + hk + tk + sk
// (verbatim R6/R7)
// ---------------------------------------------------------------------------
__global__ __launch_bounds__(256) void mo_tile(
    const ushort_t* __restrict__ Ab,
    const ushort_t* __restrict__ t1hi, const ushort_t* __restrict__ t1lo,
    const float* __restrict__ hk, const float* __restrict__ tk,
    const float* __restrict__ sk,
    float* __restrict__ out)
{
    __shared__ ushort_t At[2 * 2048];    // 2 x 4KB
    __shared__ ushort_t Bh[2 * 4096];    // 2 x 8KB
    __shared__ ushort_t Bl[2 * 4096];    // 2 x 8KB
    __shared__ float skr[NPOS];
    const int flat = xcd_swz(blockIdx.x, 896);
    const int nt = flat & 3, mt = (flat >> 2) & 7, bk = flat >> 5;
    const int b = bk / CLS, k = bk % CLS;
    const int tid = threadIdx.x;
    if (tid < NPOS) skr[tid] = sk[k * NPOS + tid];
    const int wave = tid >> 6, L = tid & 63;
    const int quad = L >> 4, l16 = L & 15;
    const int sr = L >> 3, u = (L & 7) ^ sr;
    const int srow = 2 * sr + (u >> 2);
    const int scol = (u & 3) * 8;
    const int rbase = (l16 >> 1) * 64 + ((((((l16 & 1) << 2) | quad)) ^ (l16 >> 1)) * 8);
    const int m0 = mt * 64, n0 = nt * 128;
    const int wm = (wave >> 1) * 32, wn = (wave & 1) * 64;

    const ushort_t* gA  = Ab + ((size_t)bk * NDIM + m0) * PK;
    const ushort_t* gBh = t1hi + (size_t)(b * NDIM + n0) * PK;
    const ushort_t* gBl = t1lo + (size_t)(b * NDIM + n0) * PK;

    auto stage = [&](int bo, int k0) {
        for (int s = wave; s < 20; s += 4) {
            const ushort_t* g; const ushort_t* l;
            if (s < 4)       { l = At + bo * 2048 + s * 512;         g = gA  + (size_t)(s * 16 + srow) * PK + k0 + scol; }
            else if (s < 12) { l = Bh + bo * 4096 + (s - 4) * 512;   g = gBh + (size_t)((s - 4) * 16 + srow) * PK + k0 + scol; }
            else             { l = Bl + bo * 4096 + (s - 12) * 512;  g = gBl + (size_t)((s - 12) * 16 + srow) * PK + k0 + scol; }
            glds16(g, l);
        }
    };

    floatx4 acc[2][4];
    #pragma unroll
    for (int mi = 0; mi < 2; ++mi)
        #pragma unroll
        for (int ni = 0; ni < 4; ++ni)
            #pragma unroll
            for (int r = 0; r < 4; ++r) acc[mi][ni][r] = 0.f;

    stage(0, 0);
    __syncthreads();
    int cur = 0;
    for (int t = 0; t < 9; ++t) {
        if (t < 8) stage(cur ^ 1, (t + 1) * 32);   // prefetch next tile
        short8 a[2], bh[4], bl[4];
        #pragma unroll
        for (int mi = 0; mi < 2; ++mi)
            a[mi] = *(const short8*)(At + cur * 2048 + (wm + mi * 16) * 32 + rbase);
        #pragma unroll
        for (int ni = 0; ni < 4; ++ni) {
            bh[ni] = *(const short8*)(Bh + cur * 4096 + (wn + ni * 16) * 32 + rbase);
            bl[ni] = *(const short8*)(Bl + cur * 4096 + (wn + ni * 16) * 32 + rbase);
        }
        #pragma unroll
        for (int mi = 0; mi < 2; ++mi)
            #pragma unroll
            for (int ni = 0; ni < 4; ++ni) {
                acc[mi][ni] = MFMA16(a[mi], bh[ni], acc[mi][ni]);
                acc[mi][ni] = MFMA16(a[mi], bl[ni], acc[mi][ni]);
            }
        __syncthreads();
        cur ^= 1;
    }

    const size_t obase = (size_t)bk * NDIM;
    #pragma unroll
    for (int mi = 0; mi < 2; ++mi) {
        #pragma unroll
        for (int r = 0; r < 4; ++r) {
            int row = m0 + wm + mi * 16 + quad * 4 + r;
            float hv = hk[obase + row];
            #pragma unroll
            for (int ni = 0; ni < 4; ++ni) {
                int col = n0 + wn + ni * 16 + l16;
                int d = col - row; d = d < -15 ? -15 : (d > 14 ? 14 : d); d += 15;
                out[(obase + row) * NDIM + col] = acc[mi][ni][r] + hv + tk[obase + col] + skr[d];
            }
        }
    }
}

// ---------------------------------------------------------------------------
extern "C" void kernel_launch(void* const* d_in, const int* in_sizes, int n_in,
                              void* d_out, int out_size, void* d_ws, size_t ws_size,
                              hipStream_t stream) {
    const float* x    = (const float*)d_in[0];
    const float* y    = (const float*)d_in[1];
    // d_in[2] = z : unused
    const float* m1w  = (const float*)d_in[3];
    const float* m1b  = (const float*)d_in[4];
    const float* m2w  = (const float*)d_in[5];
    const float* m2b  = (const float*)d_in[6];
    const float* hw   = (const float*)d_in[7];
    const float* hb   = (const float*)d_in[8];
    const float* tw   = (const float*)d_in[9];
    const float* tb   = (const float*)d_in[10];
    const float* biafW= (const float*)d_in[11];
    const float* W    = (const float*)d_in[12];
    const float* semb = (const float*)d_in[13];

    char* p = (char*)d_ws;
    float* hk   = (float*)p;                    p += 57344;
    float* tk   = (float*)p;                    p += 57344;
    float* skp  = (float*)p;                    p += 2048;
    float* headf= (float*)p;                    p += 1048576;
    float* tailf= (float*)p;                    p += 1048576;
    ushort_t* h1hi = (ushort_t*)p;              p += 589824;
    ushort_t* h1lo = (ushort_t*)p;              p += 589824;
    ushort_t* t1hi = (ushort_t*)p;              p += 589824;
    ushort_t* t1lo = (ushort_t*)p;              p += 589824;
    ushort_t* packW= (ushort_t*)p;              p += 3096576;  // 14*384*288*2
    ushort_t* Abuf = (ushort_t*)p;              p += 8257536;  // 28*512*288*2

    prep_proj<<<3048, 256, 0, stream>>>(x, y, m1w, m2w, hw, tw,
                                        m1b, m2b, hb, tb,
                                        biafW, packW,
                                        h1hi, h1lo, t1hi, t1lo, headf, tailf);
    mb_hk<<<802, 256, 0, stream>>>(h1hi, h1lo, packW, Abuf,
                                   headf, tailf, W, semb, hk, tk, skp);
    mo_tile<<<896, 256, 0, stream>>>(Abuf, t1hi, t1lo, hk, tk, skp,
                                     (float*)d_out);
}

// Round 9
// 175.385 us; speedup vs baseline: 1.3249x; 1.0060x over previous
//
#include <hip/hip_runtime.h>
#include <hip/hip_bf16.h>
#include <math.h>
#include <stdint.h>

#define BDIM 2
#define NDIM 512
#define HID 768
#define BIAF 256
#define CLS 14
#define DD 257   // BIAF+1
#define NPOS 30
#define SDIM 25
#define HSZ 539  // 2*257+25
#define PK 288   // padded contraction length (i and j), 9*32
#define PJ 384   // packW j-rows padding

typedef unsigned short ushort_t;
typedef __attribute__((ext_vector_type(8))) short short8;   // 8 bf16
typedef __attribute__((ext_vector_type(4))) float floatx4;  // 4 f32
typedef __attribute__((ext_vector_type(4))) unsigned short ushort4_t;

#define MFMA16(a, b, c) __builtin_amdgcn_mfma_f32_16x16x32_bf16((a), (b), (c), 0, 0, 0)

__device__ inline float bf2f(ushort_t u) {
    union { unsigned int i; float f; } c; c.i = ((unsigned)u) << 16; return c.f;
}
__device__ inline ushort_t f2bf(float f) {
    __hip_bfloat16 h = __float2bfloat16(f);
    return *(ushort_t*)&h;
}

// XCD-aware chunked swizzle (T1, bijective when nwg % 8 == 0).
__device__ inline int xcd_swz(int bid, int nwg) {
    int q = nwg >> 3;
    return (bid & 7) * q + (bid >> 3);
}

// async global->LDS, 16B per lane. LDS dest = wave-uniform base + lane*16.
__device__ inline void glds16(const ushort_t* g, const ushort_t* l) {
    __builtin_amdgcn_global_load_lds(
        (const __attribute__((address_space(1))) unsigned int*)(unsigned long long)(uintptr_t)g,
        (__attribute__((address_space(3))) unsigned int*)(unsigned int)(uintptr_t)l,
        16, 0, 0);
}

// ---------------------------------------------------------------------------
// Counted-vmcnt pipeline (T3/T4 minimum): __syncthreads lowers to
// s_waitcnt vmcnt(0)+s_barrier, draining the glds prefetch every k-step.
// Raw-asm barriers with vmcnt(N)=loads-per-wave-per-stage keep the NEXT
// stage's loads in flight across the barrier (2-step lookahead, dbuf).
//   stage(0); stage(1); vmcnt(C); barrier
//   t: compute(buf[t&1]) -> barrier -> stage(t+2,buf[t&1]); vmcnt(C) -> barrier
// "memory" clobber pins all memory ops on either side of each barrier.
// ---------------------------------------------------------------------------

// ---------------------------------------------------------------------------
// LDS seg layout (verified R1-R8): seg = [16 rows][32 cols] bf16 (1KB);
// element (r,c) at elem-off (r>>1)*64 + ((((r&1)<<2)|(c>>3)) ^ ((r>>1)&7))*8
// + (c&7).  Fragment read (l16,quad) = rbase.  glds path: linear dest +
// inverse-swizzled source.  ds_write path: swizzle applied on write address.
// ---------------------------------------------------------------------------

// ---------------------------------------------------------------------------
// prep_proj: ONE launch, three block families:
//   [0..1023]     proj: 32tok x 32feat, in-kernel f32->hi/lo split staging,
//                 24 dbuf k-steps, lgkm-only barriers (global prefetch stays
//                 in flight).  MFMA chain identical -> bit-identical.
//   [1024..2535]  repack biafW -> packW (linear PJxPK, verbatim)
//   [2536..3047]  h1/t1 pad columns (verbatim)
// ---------------------------------------------------------------------------
__global__ __launch_bounds__(256) void prep_proj(
    const float* __restrict__ x, const float* __restrict__ y,
    const float* __restrict__ m1w, const float* __restrict__ m2w,
    const float* __restrict__ hw,  const float* __restrict__ tw,
    const float* __restrict__ m1b, const float* __restrict__ m2b,
    const float* __restrict__ hb,  const float* __restrict__ tb,
    const float* __restrict__ biafW, ushort_t* __restrict__ packW,
    ushort_t* __restrict__ h1hi, ushort_t* __restrict__ h1lo,
    ushort_t* __restrict__ t1hi, ushort_t* __restrict__ t1lo,
    float* __restrict__ headf, float* __restrict__ tailf)
{
    __shared__ __align__(16) ushort_t Sh[2 * 4096];   // 16 KB (dbuf 8KB)
    const int bid = blockIdx.x;
    const int tid = threadIdx.x;

    if (bid >= 2536) {
        // ---- pads: h1/t1 cols 256..287; col 256 = 1.0 on hi planes ----
        int idx = (bid - 2536) * 256 + tid;    // 0..131071
        int plane = idx >> 15;
        int tok = (idx >> 5) & 1023;
        int c   = 256 + (idx & 31);
        ushort_t* dst = (plane == 0) ? h1hi : (plane == 1) ? h1lo : (plane == 2) ? t1hi : t1lo;
        ushort_t val = (c == 256 && (plane == 0 || plane == 2)) ? (ushort_t)0x3F80 : (ushort_t)0;
        dst[(size_t)tok * PK + c] = val;
        return;
    }
    if (bid >= 1024) {
        // ---- repack biafW[k][i][j] -> packW[k][j][i], zero-padded ----
        float (*tile)[33] = reinterpret_cast<float(*)[33]>(Sh);
        const int rb = bid - 1024;
        const int ix = rb % 9;
        const int jy = (rb / 9) % 12;
        const int k  = rb / 108;
        const int i0 = ix * 32, j0 = jy * 32;
        const int r8 = tid >> 5;
        const int c  = tid & 31;
        #pragma unroll
        for (int rr = 0; rr < 4; ++rr) {
            int r = rr * 8 + r8;
            int gi = i0 + r, gj = j0 + c;
            tile[r][c] = (gi < DD && gj < DD) ? biafW[((size_t)k * DD + gi) * DD + gj] : 0.f;
        }
        __syncthreads();
        #pragma unroll
        for (int rr = 0; rr < 4; ++rr) {
            int jr = rr * 8 + r8;
            packW[((size_t)k * PJ + (j0 + jr)) * PK + i0 + c] = f2bf(tile[c][jr]);
        }
        return;
    }

    // ---- proj: block = 32 tok x 32 feat, 24 k-steps, dbuf in-kernel split ----
    const int flat = xcd_swz(bid, 1024);
    const int ft  = flat & 7;          // 8  -> 32 feats
    const int mt2 = (flat >> 3) & 31;  // 32 -> 32 tokens
    const int proj = flat >> 8;        // 4
    const int wave = tid >> 6, L = tid & 63;
    const int quad = L >> 4, l16 = L & 15;
    const int mi = wave >> 1, fi = wave & 1;   // wave -> (16-tok frag, 16-feat frag)
    const int rbase = (l16 >> 1) * 64 + (((((l16 & 1) << 2) | quad) ^ (l16 >> 1)) * 8);

    // staging: thread -> (row srw 0..31, col-quad sc4 0..7) of the 32x32 step
    const int srw = tid >> 3, sc4 = tid & 7;
    const int sA = srw >> 4, rr = srw & 15;
    const int woffe = ((rr >> 1) * 64)
                    + (((((rr & 1) << 2) | (sc4 >> 1)) ^ ((rr >> 1) & 7)) * 8)
                    + (sc4 & 1) * 4;
    const int segA = sA * 512 + woffe;

    const float* asrc = (proj == 1) ? y : x;
    const float* wsrc = (proj == 0) ? m1w : (proj == 1) ? m2w : (proj == 2) ? hw : tw;
    const float* bias = (proj == 0) ? m1b : (proj == 1) ? m2b : (proj == 2) ? hb : tb;
    const float* aptr = asrc + (size_t)(mt2 * 32 + srw) * HID + sc4 * 4;
    const float* wptr = wsrc + (size_t)(ft * 32 + srw) * HID + sc4 * 4;

    auto cvt_write = [&](int bo, float4 av, float4 wv) {
        ushort_t* B = Sh + bo * 4096;
        float aa[4] = {av.x, av.y, av.z, av.w};
        ushort4_t ah, al;
        #pragma unroll
        for (int j = 0; j < 4; ++j) {
            ushort_t h = f2bf(aa[j]);
            ah[j] = h;
            al[j] = f2bf(aa[j] - bf2f(h));
        }
        *(ushort4_t*)(B + segA) = ah;           // Ah segs [0,1]
        *(ushort4_t*)(B + 1024 + segA) = al;    // Al segs [2,3]
        float ww[4] = {wv.x, wv.y, wv.z, wv.w};
        ushort4_t wh, wl;
        #pragma unroll
        for (int j = 0; j < 4; ++j) {
            ushort_t h = f2bf(ww[j]);
            wh[j] = h;
            wl[j] = f2bf(ww[j] - bf2f(h));
        }
        *(ushort4_t*)(B + 2048 + segA) = wh;    // Wh segs [4,5]
        *(ushort4_t*)(B + 3072 + segA) = wl;    // Wl segs [6,7]
    };

    floatx4 acc = {0.f, 0.f, 0.f, 0.f};

    // prologue: stage step 0, preload step 1
    float4 pa = *(const float4*)(aptr);
    float4 pw = *(const float4*)(wptr);
    cvt_write(0, pa, pw);
    pa = *(const float4*)(aptr + 32);
    pw = *(const float4*)(wptr + 32);
    asm volatile("s_waitcnt lgkmcnt(0)\n\ts_barrier" ::: "memory");

    int cur = 0;
    #pragma unroll 2
    for (int t = 0; t < 24; ++t) {
        if (t < 23) {
            cvt_write(cur ^ 1, pa, pw);   // stage t+1 into other buffer
            if (t < 22) {
                int k2 = (t + 2) * 32;
                pa = *(const float4*)(aptr + k2);
                pw = *(const float4*)(wptr + k2);
            }
        }
        const ushort_t* B = Sh + cur * 4096;
        short8 ah = *(const short8*)(B + mi * 512 + rbase);
        short8 al = *(const short8*)(B + 1024 + mi * 512 + rbase);
        short8 bh = *(const short8*)(B + 2048 + fi * 512 + rbase);
        short8 bl = *(const short8*)(B + 3072 + fi * 512 + rbase);
        acc = MFMA16(ah, bh, acc);
        acc = MFMA16(al, bh, acc);
        acc = MFMA16(ah, bl, acc);
        // lgkm-only barrier: ds_writes drain, global prefetch stays in flight
        asm volatile("s_waitcnt lgkmcnt(0)\n\ts_barrier" ::: "memory");
        cur ^= 1;
    }

    {
        int feat = ft * 32 + fi * 16 + l16;
        float bv = bias[feat];
        #pragma unroll
        for (int r = 0; r < 4; ++r) {
            int tok = mt2 * 32 + mi * 16 + quad * 4 + r;
            float v = acc[r] + bv;
            if (proj <= 1) {
                float g = 0.5f * v * (1.0f + erff(v * 0.70710678118654752f));
                ushort_t h = f2bf(g);
                ushort_t lo = f2bf(g - bf2f(h));
                if (proj == 0) { h1hi[(size_t)tok * PK + feat] = h; h1lo[(size_t)tok * PK + feat] = lo; }
                else           { t1hi[(size_t)tok * PK + feat] = h; t1lo[(size_t)tok * PK + feat] = lo; }
            } else {
                float lv = (v >= 0.f) ? v : 0.01f * v;
                if (proj == 2) headf[(size_t)tok * 256 + feat] = lv;
                else           tailf[(size_t)tok * 256 + feat] = lv;
            }
        }
    }
}

// ---------------------------------------------------------------------------
// mb_hk: fused mb_tile (blocks 0..671, XCD-swizzled) + hk_tk_sk (672..801).
// mb k-loop: counted-vmcnt two-barrier pipeline (per-wave loads/stage:
// waves 0,1 = 4; waves 2,3 = 3 -> wave-uniform vmcnt variants).
// ---------------------------------------------------------------------------
__global__ __launch_bounds__(256) void mb_hk(
    const ushort_t* __restrict__ h1hi, const ushort_t* __restrict__ h1lo,
    const ushort_t* __restrict__ packW,
    ushort_t* __restrict__ Ab,
    const float* __restrict__ headf, const float* __restrict__ tailf,
    const float* __restrict__ W, const float* __restrict__ semb,
    float* __restrict__ hk, float* __restrict__ tk, float* __restrict__ skp)
{
    const int bid = blockIdx.x;
    if (bid >= 672) {
        const int hb = bid - 672;           // 0..129
        if (hb >= 128) {
            int idx = (hb - 128) * 256 + threadIdx.x;
            if (idx < CLS * NPOS) {
                int k = idx / NPOS, d = idx % NPOS;
                float acc = 0.f;
                for (int h = 0; h < SDIM; ++h)
                    acc += semb[d*SDIM + h] * W[k*HSZ + 2*DD + h];
                skp[idx] = acc;
            }
            return;
        }
        int p = hb * 256 + threadIdx.x;      // 32768 items
        int which = p >> 14;                 // 0=hk, 1=tk
        int idx = p & 16383;
        int tok = idx >> 4;
        int k = idx & 15;
        if (k >= CLS) return;
        const float* row = (which ? tailf : headf) + (size_t)tok * 256;
        const float* wr = W + (size_t)k * HSZ + (which ? DD : 0);
        float acc = 0.f;
        for (int f4 = 0; f4 < 64; ++f4) {
            float4 rv = *(const float4*)(row + f4 * 4);
            acc += rv.x * wr[f4*4] + rv.y * wr[f4*4+1] + rv.z * wr[f4*4+2] + rv.w * wr[f4*4+3];
        }
        acc += wr[256];
        float* dst = which ? tk : hk;
        dst[(size_t)(tok >> 9) * CLS * NDIM + (size_t)k * NDIM + (tok & 511)] = acc;
        return;
    }

    // ---- mb_tile, counted-vmcnt dbuf pipeline, XCD-swizzled ----
    __shared__ ushort_t Ah[2 * 2048];   // 2 x 4KB
    __shared__ ushort_t Al[2 * 2048];   // 2 x 4KB
    __shared__ ushort_t Bt[2 * 3072];   // 2 x 6KB
    const int flat = xcd_swz(bid, 672);
    const int jt = flat % 3, mt = (flat / 3) % 8, bk = flat / 24;
    const int b = bk / CLS, k = bk % CLS;
    const int tid = threadIdx.x;
    const int wave = tid >> 6, L = tid & 63;
    const int quad = L >> 4, l16 = L & 15;
    const int sr = L >> 3, u = (L & 7) ^ sr;
    const int srow = 2 * sr + (u >> 2);        // row within 16-row segment
    const int scol = (u & 3) * 8;              // element col within 32
    const int rbase = (l16 >> 1) * 64 + ((((((l16 & 1) << 2) | quad)) ^ (l16 >> 1)) * 8);
    const int m0 = mt * 64, j0 = jt * 96;
    const int wm = (wave >> 1) * 32, wj = (wave & 1) * 48;

    const ushort_t* gAh = h1hi + (size_t)(b * NDIM + m0) * PK;
    const ushort_t* gAl = h1lo + (size_t)(b * NDIM + m0) * PK;
    const ushort_t* gB  = packW + ((size_t)k * PJ + j0) * PK;

    auto stage = [&](int bo, int k0) {
        for (int s = wave; s < 14; s += 4) {
            const ushort_t* g; const ushort_t* l;
            if (s < 4)      { l = Ah + bo * 2048 + s * 512;       g = gAh + (size_t)(s * 16 + srow) * PK + k0 + scol; }
            else if (s < 8) { l = Al + bo * 2048 + (s - 4) * 512; g = gAl + (size_t)((s - 4) * 16 + srow) * PK + k0 + scol; }
            else            { l = Bt + bo * 3072 + (s - 8) * 512; g = gB  + (size_t)((s - 8) * 16 + srow) * PK + k0 + scol; }
            glds16(g, l);
        }
    };

    floatx4 acc[2][3];
    #pragma unroll
    for (int mi = 0; mi < 2; ++mi)
        #pragma unroll
        for (int ni = 0; ni < 3; ++ni)
            #pragma unroll
            for (int r = 0; r < 4; ++r) acc[mi][ni][r] = 0.f;

    stage(0, 0);
    stage(1, 32);
    if (wave < 2) asm volatile("s_waitcnt vmcnt(4)\n\ts_barrier" ::: "memory");
    else          asm volatile("s_waitcnt vmcnt(3)\n\ts_barrier" ::: "memory");

    int cur = 0;
    for (int t = 0; t < 9; ++t) {
        short8 ah[2], al[2], bb[3];
        #pragma unroll
        for (int mi = 0; mi < 2; ++mi) {
            ah[mi] = *(const short8*)(Ah + cur * 2048 + (wm + mi * 16) * 32 + rbase);
            al[mi] = *(const short8*)(Al + cur * 2048 + (wm + mi * 16) * 32 + rbase);
        }
        #pragma unroll
        for (int ni = 0; ni < 3; ++ni)
            bb[ni] = *(const short8*)(Bt + cur * 3072 + (wj + ni * 16) * 32 + rbase);
        #pragma unroll
        for (int mi = 0; mi < 2; ++mi)
            #pragma unroll
            for (int ni = 0; ni < 3; ++ni) {
                acc[mi][ni] = MFMA16(ah[mi], bb[ni], acc[mi][ni]);
                acc[mi][ni] = MFMA16(al[mi], bb[ni], acc[mi][ni]);
            }
        if (t == 8) break;
        asm volatile("s_barrier" ::: "memory");          // all waves done reading buf[cur]
        if (t < 7) {
            stage(cur, (t + 2) * 32);                    // refill freed buffer
            if (wave < 2) asm volatile("s_waitcnt vmcnt(4)\n\ts_barrier" ::: "memory");
            else          asm volatile("s_waitcnt vmcnt(3)\n\ts_barrier" ::: "memory");
        } else {
            asm volatile("s_waitcnt vmcnt(0)\n\ts_barrier" ::: "memory");
        }
        cur ^= 1;
    }

    ushort_t* Aout = Ab + (size_t)bk * NDIM * PK;
    #pragma unroll
    for (int mi = 0; mi < 2; ++mi) {
        #pragma unroll
        for (int r = 0; r < 4; ++r) {
            int row = m0 + wm + mi * 16 + quad * 4 + r;
            #pragma unroll
            for (int ni = 0; ni < 3; ++ni) {
                int col = j0 + wj + ni * 16 + l16;
                Aout[(size_t)row * PK + col] = f2bf(acc[mi][ni][r]);
            }
        }
    }
}

// ---------------------------------------------------------------------------
// mo_tile: out[bk][m][n] = sum_j A[bk][m][j]*t1[b][n][j] + hk + tk + sk
// counted-vmcnt two-barrier pipeline (5 loads/wave/stage -> vmcnt(5)).
// ---------------------------------------------------------------------------
__global__ __launch_bounds__(256) void mo_tile(
    const ushort_t* __restrict__ Ab,
    const ushort_t* __restrict__ t1hi, const ushort_t* __restrict__ t1lo,
    const float* __restrict__ hk, const float* __restrict__ tk,
    const float* __restrict__ sk,
    float* __restrict__ out)
{
    __shared__ ushort_t At[2 * 2048];    // 2 x 4KB
    __shared__ ushort_t Bh[2 * 4096];    // 2 x 8KB
    __shared__ ushort_t Bl[2 * 4096];    // 2 x 8KB
    __shared__ float skr[NPOS];
    const int flat = xcd_swz(blockIdx.x, 896);
    const int nt = flat & 3, mt = (flat >> 2) & 7, bk = flat >> 5;
    const int b = bk / CLS, k = bk % CLS;
    const int tid = threadIdx.x;
    if (tid < NPOS) skr[tid] = sk[k * NPOS + tid];
    const int wave = tid >> 6, L = tid & 63;
    const int quad = L >> 4, l16 = L & 15;
    const int sr = L >> 3, u = (L & 7) ^ sr;
    const int srow = 2 * sr + (u >> 2);
    const int scol = (u & 3) * 8;
    const int rbase = (l16 >> 1) * 64 + ((((((l16 & 1) << 2) | quad)) ^ (l16 >> 1)) * 8);
    const int m0 = mt * 64, n0 = nt * 128;
    const int wm = (wave >> 1) * 32, wn = (wave & 1) * 64;

    const ushort_t* gA  = Ab + ((size_t)bk * NDIM + m0) * PK;
    const ushort_t* gBh = t1hi + (size_t)(b * NDIM + n0) * PK;
    const ushort_t* gBl = t1lo + (size_t)(b * NDIM + n0) * PK;

    auto stage = [&](int bo, int k0) {
        for (int s = wave; s < 20; s += 4) {
            const ushort_t* g; const ushort_t* l;
            if (s < 4)       { l = At + bo * 2048 + s * 512;         g = gA  + (size_t)(s * 16 + srow) * PK + k0 + scol; }
            else if (s < 12) { l = Bh + bo * 4096 + (s - 4) * 512;   g = gBh + (size_t)((s - 4) * 16 + srow) * PK + k0 + scol; }
            else             { l = Bl + bo * 4096 + (s - 12) * 512;  g = gBl + (size_t)((s - 12) * 16 + srow) * PK + k0 + scol; }
            glds16(g, l);
        }
    };

    floatx4 acc[2][4];
    #pragma unroll
    for (int mi = 0; mi < 2; ++mi)
        #pragma unroll
        for (int ni = 0; ni < 4; ++ni)
            #pragma unroll
            for (int r = 0; r < 4; ++r) acc[mi][ni][r] = 0.f;

    stage(0, 0);
    stage(1, 32);
    asm volatile("s_waitcnt vmcnt(5)\n\ts_barrier" ::: "memory");

    int cur = 0;
    for (int t = 0; t < 9; ++t) {
        short8 a[2], bh[4], bl[4];
        #pragma unroll
        for (int mi = 0; mi < 2; ++mi)
            a[mi] = *(const short8*)(At + cur * 2048 + (wm + mi * 16) * 32 + rbase);
        #pragma unroll
        for (int ni = 0; ni < 4; ++ni) {
            bh[ni] = *(const short8*)(Bh + cur * 4096 + (wn + ni * 16) * 32 + rbase);
            bl[ni] = *(const short8*)(Bl + cur * 4096 + (wn + ni * 16) * 32 + rbase);
        }
        #pragma unroll
        for (int mi = 0; mi < 2; ++mi)
            #pragma unroll
            for (int ni = 0; ni < 4; ++ni) {
                acc[mi][ni] = MFMA16(a[mi], bh[ni], acc[mi][ni]);
                acc[mi][ni] = MFMA16(a[mi], bl[ni], acc[mi][ni]);
            }
        if (t == 8) break;
        asm volatile("s_barrier" ::: "memory");          // all waves done reading buf[cur]
        if (t < 7) {
            stage(cur, (t + 2) * 32);                    // refill freed buffer
            asm volatile("s_waitcnt vmcnt(5)\n\ts_barrier" ::: "memory");
        } else {
            asm volatile("s_waitcnt vmcnt(0)\n\ts_barrier" ::: "memory");
        }
        cur ^= 1;
    }

    const size_t obase = (size_t)bk * NDIM;
    #pragma unroll
    for (int mi = 0; mi < 2; ++mi) {
        #pragma unroll
        for (int r = 0; r < 4; ++r) {
            int row = m0 + wm + mi * 16 + quad * 4 + r;
            float hv = hk[obase + row];
            #pragma unroll
            for (int ni = 0; ni < 4; ++ni) {
                int col = n0 + wn + ni * 16 + l16;
                int d = col - row; d = d < -15 ? -15 : (d > 14 ? 14 : d); d += 15;
                out[(obase + row) * NDIM + col] = acc[mi][ni][r] + hv + tk[obase + col] + skr[d];
            }
        }
    }
}

// ---------------------------------------------------------------------------
extern "C" void kernel_launch(void* const* d_in, const int* in_sizes, int n_in,
                              void* d_out, int out_size, void* d_ws, size_t ws_size,
                              hipStream_t stream) {
    const float* x    = (const float*)d_in[0];
    const float* y    = (const float*)d_in[1];
    // d_in[2] = z : unused
    const float* m1w  = (const float*)d_in[3];
    const float* m1b  = (const float*)d_in[4];
    const float* m2w  = (const float*)d_in[5];
    const float* m2b  = (const float*)d_in[6];
    const float* hw   = (const float*)d_in[7];
    const float* hb   = (const float*)d_in[8];
    const float* tw   = (const float*)d_in[9];
    const float* tb   = (const float*)d_in[10];
    const float* biafW= (const float*)d_in[11];
    const float* W    = (const float*)d_in[12];
    const float* semb = (const float*)d_in[13];

    char* p = (char*)d_ws;
    float* hk   = (float*)p;                    p += 57344;
    float* tk   = (float*)p;                    p += 57344;
    float* skp  = (float*)p;                    p += 2048;
    float* headf= (float*)p;                    p += 1048576;
    float* tailf= (float*)p;                    p += 1048576;
    ushort_t* h1hi = (ushort_t*)p;              p += 589824;
    ushort_t* h1lo = (ushort_t*)p;              p += 589824;
    ushort_t* t1hi = (ushort_t*)p;              p += 589824;
    ushort_t* t1lo = (ushort_t*)p;              p += 589824;
    ushort_t* packW= (ushort_t*)p;              p += 3096576;  // 14*384*288*2
    ushort_t* Abuf = (ushort_t*)p;              p += 8257536;  // 28*512*288*2

    prep_proj<<<3048, 256, 0, stream>>>(x, y, m1w, m2w, hw, tw,
                                        m1b, m2b, hb, tb,
                                        biafW, packW,
                                        h1hi, h1lo, t1hi, t1lo, headf, tailf);
    mb_hk<<<802, 256, 0, stream>>>(h1hi, h1lo, packW, Abuf,
                                   headf, tailf, W, semb, hk, tk, skp);
    mo_tile<<<896, 256, 0, stream>>>(Abuf, t1hi, t1lo, hk, tk, skp,
                                     (float*)d_out);
}